// Round 5
// baseline (259.409 us; speedup 1.0000x reference)
//
#include <hip/hip_runtime.h>
#include <hip/hip_bf16.h>

#define BATCH 16
#define SEQ   1024
#define DIM   1024

typedef __attribute__((ext_vector_type(8))) short bf16x8;
typedef __attribute__((ext_vector_type(4))) float f32x4;
typedef __attribute__((ext_vector_type(4))) unsigned short us4;

__device__ __forceinline__ float bfu2f(unsigned short u) {
  union { unsigned int i; float f; } c; c.i = ((unsigned int)u) << 16; return c.f;
}
__device__ __forceinline__ unsigned short f2bfu(float f) {
  union { float f; unsigned int i; } c; c.f = f;
  return (unsigned short)((c.i + 0x7FFFu + ((c.i >> 16) & 1u)) >> 16);
}
__device__ __forceinline__ void async16(void* lds, const void* g) {
  __builtin_amdgcn_global_load_lds(
      (const __attribute__((address_space(1))) unsigned int*)g,
      (__attribute__((address_space(3))) unsigned int*)lds, 16, 0, 0);
}

// ---------------- cast fp32 -> bf16 for x and Wv in one dispatch ----------------
__global__ void cast_xw_kernel(const float* __restrict__ x, const float* __restrict__ Wv,
                               unsigned short* __restrict__ xb,
                               unsigned short* __restrict__ Wvb, int x4) {
  int i = blockIdx.x * blockDim.x + threadIdx.x;
  const float* in; unsigned short* out; int j;
  if (i < x4) { in = x; out = xb; j = i; }
  else { in = Wv; out = Wvb; j = i - x4; }
  f32x4 v = ((const f32x4*)in)[j];
  us4 o;
  o[0] = f2bfu(v[0]); o[1] = f2bfu(v[1]); o[2] = f2bfu(v[2]); o[3] = f2bfu(v[3]);
  ((us4*)out)[j] = o;
}

// ---------------- transpose-cast: out[i,h] = bf16(in[h,i]) for Wq, Wk ----------------
__global__ void castT_kernel(const float* __restrict__ Wq, const float* __restrict__ Wk,
                             unsigned short* __restrict__ WqT,
                             unsigned short* __restrict__ WkT) {
  const float* in = (blockIdx.z == 0) ? Wq : Wk;
  unsigned short* out = (blockIdx.z == 0) ? WqT : WkT;
  __shared__ float t[64][65];
  const int h0 = blockIdx.x * 64, i0 = blockIdx.y * 64;
  const int tid = threadIdx.x;
  const int sub = tid >> 4, c4 = tid & 15;
#pragma unroll
  for (int p = 0; p < 4; ++p) {
    const int row = p * 16 + sub;
    f32x4 v = *(const f32x4*)(in + (size_t)(h0 + row) * DIM + i0 + c4 * 4);
    t[row][c4 * 4 + 0] = v[0]; t[row][c4 * 4 + 1] = v[1];
    t[row][c4 * 4 + 2] = v[2]; t[row][c4 * 4 + 3] = v[3];
  }
  __syncthreads();
#pragma unroll
  for (int p = 0; p < 4; ++p) {
    const int orow = p * 16 + sub;
    us4 o;
    o[0] = f2bfu(t[c4 * 4 + 0][orow]);
    o[1] = f2bfu(t[c4 * 4 + 1][orow]);
    o[2] = f2bfu(t[c4 * 4 + 2][orow]);
    o[3] = f2bfu(t[c4 * 4 + 3][orow]);
    *(us4*)(out + (size_t)(i0 + orow) * DIM + h0 + c4 * 4) = o;
  }
}

// ---------------- t1 = WqT·bk, t2 = WkT·bq (row-dots) ----------------
__global__ void t12_kernel(const unsigned short* __restrict__ WqT,
                           const unsigned short* __restrict__ WkT,
                           const float* __restrict__ bq, const float* __restrict__ bk,
                           float* __restrict__ t1, float* __restrict__ t2) {
  const int y = blockIdx.y;
  const unsigned short* Wt = y ? WkT : WqT;
  const float* vec = y ? bq : bk;
  float* tout = y ? t2 : t1;
  const int wave = threadIdx.x >> 6, lane = threadIdx.x & 63;
  const int i = blockIdx.x * 4 + wave;
  const us4* wr = (const us4*)(Wt + (size_t)i * DIM);
  float s = 0.f;
#pragma unroll
  for (int t = 0; t < 4; ++t) {
    us4 w4 = wr[lane + 64 * t];
    f32x4 b4 = *(const f32x4*)(vec + (lane + 64 * t) * 4);
    s += bfu2f(w4[0]) * b4[0] + bfu2f(w4[1]) * b4[1] +
         bfu2f(w4[2]) * b4[2] + bfu2f(w4[3]) * b4[3];
  }
#pragma unroll
  for (int o = 32; o; o >>= 1) s += __shfl_down(s, o);
  if (lane == 0) tout[i] = s;
}

// ---------------- a[bn]=scale*(x_row·t1 + bq·bk); c[bn]=scale*(x_row·t2) ----------------
__global__ void ac_kernel(const unsigned short* __restrict__ xb,
                          const float* __restrict__ t1, const float* __restrict__ t2,
                          const float* __restrict__ bq, const float* __restrict__ bk,
                          float* __restrict__ a, float* __restrict__ c) {
  const float scale = 0.03125f;
  const int tid = threadIdx.x;
  const int wave = tid >> 6, lane = tid & 63;
  float dp = 0.f;
  for (int i = tid; i < DIM; i += 256) dp += bq[i] * bk[i];
#pragma unroll
  for (int o = 32; o; o >>= 1) dp += __shfl_down(dp, o);
  __shared__ float dred[4];
  if ((tid & 63) == 0) dred[tid >> 6] = dp;
  __syncthreads();
  const float d = dred[0] + dred[1] + dred[2] + dred[3];
  float t1r[16], t2r[16];
#pragma unroll
  for (int t = 0; t < 4; ++t) {
    f32x4 v1 = *(const f32x4*)(t1 + (lane + 64 * t) * 4);
    f32x4 v2 = *(const f32x4*)(t2 + (lane + 64 * t) * 4);
#pragma unroll
    for (int j = 0; j < 4; ++j) { t1r[t * 4 + j] = v1[j]; t2r[t * 4 + j] = v2[j]; }
  }
  for (int rr = 0; rr < 16; ++rr) {
    const int row = blockIdx.x * 64 + wave * 16 + rr;
    const us4* xr = (const us4*)(xb + (size_t)row * DIM);
    float sa = 0.f, sc = 0.f;
#pragma unroll
    for (int t = 0; t < 4; ++t) {
      us4 v = xr[lane + 64 * t];
#pragma unroll
      for (int j = 0; j < 4; ++j) {
        const float f = bfu2f(v[j]);
        sa += f * t1r[t * 4 + j];
        sc += f * t2r[t * 4 + j];
      }
    }
#pragma unroll
    for (int o = 32; o; o >>= 1) { sa += __shfl_down(sa, o); sc += __shfl_down(sc, o); }
    if (lane == 0) {
      a[row] = scale * (sa + d);
      c[row] = scale * sc;
    }
  }
}

// ---------------- path-pool weights w[b,j]; zero-inits denom (+zbias via block 0) ----------------
__global__ void pathw_kernel(const int* __restrict__ pos, float* __restrict__ w,
                             float* __restrict__ denom, float* __restrict__ zbias) {
  const int b = blockIdx.x;
  __shared__ int ps[SEQ];
  __shared__ int mcnt;
  const int tid = threadIdx.x;
  if (tid == 0) mcnt = 0;
  __syncthreads();
  if (b == 0)
    for (int i = tid; i < DIM; i += 256) zbias[i] = 0.f;
  for (int i = tid; i < SEQ; i += 256) {
    ps[i] = pos[b * SEQ + i];
    denom[b * SEQ + i] = 0.f;
  }
  __syncthreads();
  int c = 0;
  for (int i = tid; i < SEQ; i += 256) c += ps[i];
  for (int o = 32; o; o >>= 1) c += __shfl_down(c, o);
  if ((tid & 63) == 0) atomicAdd(&mcnt, c);
  __syncthreads();
  const float invM = 1.0f / (float)mcnt;
  for (int j = tid; j < SEQ; j += 256) {
    float a = 0.f;
#pragma unroll
    for (int di = -1; di <= 1; ++di) {
      int i = j + di;
      if (i < 0 || i >= SEQ) continue;
      if (!ps[i]) continue;
      int s, e;
      if (i < 2) { s = 0; e = (i == 0) ? 2 : 3; }
      else { s = (ps[i - 2] == 1) ? i : (i - 1); e = i + 2; if (e > SEQ) e = SEQ; }
      if (s <= j && j < e) a += 1.0f / (float)(e - s);
    }
    w[b * SEQ + j] = a * invM;
  }
}

// ---------------- bf16 NT GEMM: C = bf16((A @ W^T + bias)*alpha) ----------------
__global__ void proj_gemm(const unsigned short* __restrict__ A,
                          const unsigned short* __restrict__ W,
                          const float* __restrict__ bias, float alpha,
                          unsigned short* __restrict__ C, int M, int N, int K)
{
  __shared__ __align__(16) char smem[16896];
  unsigned short* As = (unsigned short*)smem;
  unsigned short* Bs = (unsigned short*)(smem + 8192);
  float* Sl = (float*)smem;
  const int tid = threadIdx.x;
  const int wave = tid >> 6, lane = tid & 63;
  const int lr = lane & 15, lg = lane >> 4;
  const int wr = wave >> 1, wc = wave & 1;
  const int m0 = blockIdx.x * 128, n0 = blockIdx.y * 128;
  const int off0 = tid * 16, off1 = 4096 + tid * 16;
  const int r0 = off0 >> 6, ke0 = (off0 >> 1) & 31;
  const int r1 = off1 >> 6, ke1 = (off1 >> 1) & 31;
  f32x4 acc[4][4] = {};
  for (int kk = 0; kk < K; kk += 32) {
    async16((char*)As + off0, A + (size_t)(m0 + r0) * K + kk + ke0);
    async16((char*)As + off1, A + (size_t)(m0 + r1) * K + kk + ke1);
    async16((char*)Bs + off0, W + (size_t)(n0 + r0) * K + kk + ke0);
    async16((char*)Bs + off1, W + (size_t)(n0 + r1) * K + kk + ke1);
    __syncthreads();
    bf16x8 af[4], bfv[4];
#pragma unroll
    for (int i = 0; i < 4; ++i) {
      af[i]  = *(const bf16x8*)((const char*)As + ((wr * 64 + i * 16 + lr) << 6) + (lg << 4));
      bfv[i] = *(const bf16x8*)((const char*)Bs + ((wc * 64 + i * 16 + lr) << 6) + (lg << 4));
    }
#pragma unroll
    for (int i = 0; i < 4; ++i)
#pragma unroll
      for (int j = 0; j < 4; ++j)
        acc[i][j] = __builtin_amdgcn_mfma_f32_16x16x32_bf16(af[i], bfv[j], acc[i][j], 0, 0, 0);
    __syncthreads();
  }
#pragma unroll
  for (int p = 0; p < 4; ++p) {
    __syncthreads();
    if (wr == (p >> 1)) {
      const int ibase = (p & 1) * 2;
#pragma unroll
      for (int ii = 0; ii < 2; ++ii) {
        const int i = ibase + ii;
#pragma unroll
        for (int j = 0; j < 4; ++j)
#pragma unroll
          for (int r = 0; r < 4; ++r)
            Sl[(ii * 16 + lg * 4 + r) * 132 + wc * 64 + j * 16 + lr] = acc[i][j][r];
      }
    }
    __syncthreads();
#pragma unroll
    for (int it = 0; it < 4; ++it) {
      const int v = tid + it * 256;
      const int lrow = v >> 5, c4 = v & 31;
      const int grow = m0 + p * 32 + lrow;
      const int col = n0 + c4 * 4;
      const f32x4 s4 = *(const f32x4*)(&Sl[lrow * 132 + c4 * 4]);
      const f32x4 b4 = *(const f32x4*)(bias + col);
      us4 o;
      o[0] = f2bfu((s4[0] + b4[0]) * alpha);
      o[1] = f2bfu((s4[1] + b4[1]) * alpha);
      o[2] = f2bfu((s4[2] + b4[2]) * alpha);
      o[3] = f2bfu((s4[3] + b4[3]) * alpha);
      *(us4*)(C + (size_t)grow * N + col) = o;
    }
  }
}

// ---------------- per-batch E = exp(z@x^T + a_n + c_m + atom + var), fused rowsum.
// Two-tile pipeline: each block does tiles (m0,n0a) and (m0,n0b=n0a+128);
// tile1's epilogue chunk-iterations are interleaved into tile2's K-loop so
// graph reads/exp/E-stores overlap the MFMA pipe. Sl is a separate LDS region.
__global__ __launch_bounds__(256, 2)
void qk_exp_kernel(const unsigned short* __restrict__ z,
                   const unsigned short* __restrict__ xb,
                   const float* __restrict__ ag,
                   const float* __restrict__ vg,
                   const float* __restrict__ av,
                   const float* __restrict__ cv,
                   unsigned short* __restrict__ E,
                   float* __restrict__ denom)
{
  __shared__ __align__(16) unsigned short As[128 * 32];
  __shared__ __align__(16) unsigned short Bs[128 * 32];
  __shared__ __align__(16) float Sl[32 * 132];
  const int b = blockIdx.z;
  const unsigned short* Aq = z + ((size_t)b << 20);
  const unsigned short* Bk = xb + ((size_t)b << 20);
  const int tid = threadIdx.x;
  const int wave = tid >> 6, lane = tid & 63;
  const int lr = lane & 15, lg = lane >> 4;
  const int wr = wave >> 1, wc = wave & 1;
  const int m0 = blockIdx.y * 128;
  const int n0a = blockIdx.x * 256, n0b = n0a + 128;
  const int off0 = tid * 16, off1 = 4096 + tid * 16;
  const int r0 = off0 >> 6, ke0 = (off0 >> 1) & 31;
  const int r1 = off1 >> 6, ke1 = (off1 >> 1) & 31;
  const float* agb = ag + ((size_t)b << 20);
  const float* vgb = vg + ((size_t)b << 20);
  unsigned short* Eb = E + ((size_t)b << 20);
  float* dnb = denom + b * SEQ;
  const float* avb = av + b * SEQ;
  const float* cvb = cv + b * SEQ;

  // one epilogue chunk-iteration: 256 threads cover 32 rows x 128 cols
  auto chunk = [&](int p, int it, int nb) {
    const int v = tid + it * 256;
    const int lrow = v >> 5, c4 = v & 31;
    const int grow = m0 + p * 32 + lrow;
    const size_t base = (size_t)grow * SEQ + nb + c4 * 4;
    const f32x4 a4 = *(const f32x4*)(agb + base);
    const f32x4 g4 = *(const f32x4*)(vgb + base);
    const f32x4 c4v = *(const f32x4*)(cvb + nb + c4 * 4);
    const float arow = avb[grow];
    const f32x4 s4 = *(const f32x4*)(&Sl[lrow * 132 + c4 * 4]);
    const float e0 = __expf(s4[0] + a4[0] + g4[0] + arow + c4v[0]);
    const float e1 = __expf(s4[1] + a4[1] + g4[1] + arow + c4v[1]);
    const float e2 = __expf(s4[2] + a4[2] + g4[2] + arow + c4v[2]);
    const float e3 = __expf(s4[3] + a4[3] + g4[3] + arow + c4v[3]);
    us4 o;
    o[0] = f2bfu(e0); o[1] = f2bfu(e1); o[2] = f2bfu(e2); o[3] = f2bfu(e3);
    *(us4*)(Eb + base) = o;
    float rs = e0 + e1 + e2 + e3;
#pragma unroll
    for (int o2 = 16; o2; o2 >>= 1) rs += __shfl_down(rs, o2, 32);
    if ((tid & 31) == 0) atomicAdd(&dnb[grow], rs);
  };

  f32x4 acc1[4][4] = {}, acc2[4][4] = {};

  // ---- tile1 main K-loop ----
  for (int kk = 0; kk < DIM; kk += 32) {
    async16((char*)As + off0, Aq + (size_t)(m0 + r0) * DIM + kk + ke0);
    async16((char*)As + off1, Aq + (size_t)(m0 + r1) * DIM + kk + ke1);
    async16((char*)Bs + off0, Bk + (size_t)(n0a + r0) * DIM + kk + ke0);
    async16((char*)Bs + off1, Bk + (size_t)(n0a + r1) * DIM + kk + ke1);
    __syncthreads();
    bf16x8 af[4], bfv[4];
#pragma unroll
    for (int i = 0; i < 4; ++i) {
      af[i]  = *(const bf16x8*)((const char*)As + ((wr * 64 + i * 16 + lr) << 6) + (lg << 4));
      bfv[i] = *(const bf16x8*)((const char*)Bs + ((wc * 64 + i * 16 + lr) << 6) + (lg << 4));
    }
#pragma unroll
    for (int i = 0; i < 4; ++i)
#pragma unroll
      for (int j = 0; j < 4; ++j)
        acc1[i][j] = __builtin_amdgcn_mfma_f32_16x16x32_bf16(af[i], bfv[j], acc1[i][j], 0, 0, 0);
    __syncthreads();
  }

  // ---- fused: tile2 main K-loop + tile1 epilogue (4 super-blocks of 8 K-steps) ----
#pragma unroll
  for (int p = 0; p < 4; ++p) {
    if (wr == (p >> 1)) {
      const int ibase = (p & 1) * 2;
#pragma unroll
      for (int ii = 0; ii < 2; ++ii) {
        const int i = ibase + ii;
#pragma unroll
        for (int j = 0; j < 4; ++j)
#pragma unroll
          for (int r = 0; r < 4; ++r)
            Sl[(ii * 16 + lg * 4 + r) * 132 + wc * 64 + j * 16 + lr] = acc1[i][j][r];
      }
    }
    __syncthreads();   // Sl chunk visible to all
#pragma unroll
    for (int ks = 0; ks < 8; ++ks) {
      const int kk = (p * 8 + ks) * 32;
      async16((char*)As + off0, Aq + (size_t)(m0 + r0) * DIM + kk + ke0);
      async16((char*)As + off1, Aq + (size_t)(m0 + r1) * DIM + kk + ke1);
      async16((char*)Bs + off0, Bk + (size_t)(n0b + r0) * DIM + kk + ke0);
      async16((char*)Bs + off1, Bk + (size_t)(n0b + r1) * DIM + kk + ke1);
      __syncthreads();
      bf16x8 af[4], bfv[4];
#pragma unroll
      for (int i = 0; i < 4; ++i) {
        af[i]  = *(const bf16x8*)((const char*)As + ((wr * 64 + i * 16 + lr) << 6) + (lg << 4));
        bfv[i] = *(const bf16x8*)((const char*)Bs + ((wc * 64 + i * 16 + lr) << 6) + (lg << 4));
      }
      if ((ks & 1) == 0) chunk(p, ks >> 1, n0a);   // overlap tile1 epilogue with MFMAs
#pragma unroll
      for (int i = 0; i < 4; ++i)
#pragma unroll
        for (int j = 0; j < 4; ++j)
          acc2[i][j] = __builtin_amdgcn_mfma_f32_16x16x32_bf16(af[i], bfv[j], acc2[i][j], 0, 0, 0);
      __syncthreads();
    }
  }

  // ---- tile2 trailing epilogue ----
#pragma unroll
  for (int p = 0; p < 4; ++p) {
    if (wr == (p >> 1)) {
      const int ibase = (p & 1) * 2;
#pragma unroll
      for (int ii = 0; ii < 2; ++ii) {
        const int i = ibase + ii;
#pragma unroll
        for (int j = 0; j < 4; ++j)
#pragma unroll
          for (int r = 0; r < 4; ++r)
            Sl[(ii * 16 + lg * 4 + r) * 132 + wc * 64 + j * 16 + lr] = acc2[i][j][r];
      }
    }
    __syncthreads();
#pragma unroll
    for (int it = 0; it < 4; ++it) chunk(p, it, n0b);
    __syncthreads();
  }
}

// ---------------- weighted column sum: out[b,m] = sum_n c[b,n]*Mt[b,n,m]
// weights: if dv   -> c[n] = wv[n]/dv[n]
//          if pin  -> c[n] = sum_j pin[(b*8+j)*1024 + n]   (inline u-reduction)
__global__ void wcolsum_part(const unsigned short* __restrict__ Mt,
                             const float* __restrict__ wv,
                             const float* __restrict__ dv,
                             const float* __restrict__ pin,
                             float* __restrict__ part) {
  const int b = blockIdx.z;
  const int nc = blockIdx.y;
  const int m = blockIdx.x * 256 + threadIdx.x;
  __shared__ float c[128];
  const int tid = threadIdx.x;
  if (tid < 128) {
    const int n = nc * 128 + tid;
    float cvw;
    if (pin) {
      cvw = 0.f;
#pragma unroll
      for (int j = 0; j < 8; ++j) cvw += pin[(size_t)((b * 8 + j) << 10) + n];
    } else {
      cvw = wv[b * SEQ + n];
      if (dv) cvw /= dv[b * SEQ + n];
    }
    c[tid] = cvw;
  }
  __syncthreads();
  const unsigned short* p = Mt + ((size_t)b << 20) + ((size_t)(nc * 128) << 10) + m;
  float acc = 0.f;
#pragma unroll 8
  for (int n = 0; n < 128; ++n) acc += c[n] * bfu2f(p[(size_t)n << 10]);
  part[(size_t)((b * 8 + nc) << 10) + m] = acc;
}

__global__ void wcolsum_reduce(const float* __restrict__ part, float* __restrict__ out) {
  const int b = blockIdx.y;
  const int m = blockIdx.x * 256 + threadIdx.x;
  float s = 0.f;
#pragma unroll
  for (int nc = 0; nc < 8; ++nc) s += part[(size_t)((b * 8 + nc) << 10) + m];
  out[b * SEQ + m] = s;
}

// ---------------- item[b,h] = sum_d y[b,d]*Wv[h,d] + (sum u)*bv[h]
// sum_u computed inline from part1 (u never materialized).
__global__ void item_kernel(const float* __restrict__ y, const float* __restrict__ part1,
                            const unsigned short* __restrict__ Wvb,
                            const float* __restrict__ bv, float* __restrict__ item) {
  const int b = blockIdx.x;
  const int hblk = blockIdx.y;
  __shared__ float ys[DIM];
  __shared__ float sred[4];
  const int tid = threadIdx.x;
  float part = 0.f;
  for (int i = tid; i < DIM; i += 256) ys[i] = y[b * DIM + i];
  for (int i = tid; i < 8 * SEQ; i += 256) part += part1[(size_t)(b * 8) * SEQ + i];
  for (int o = 32; o; o >>= 1) part += __shfl_down(part, o);
  if ((tid & 63) == 0) sred[tid >> 6] = part;
  __syncthreads();
  const float su = sred[0] + sred[1] + sred[2] + sred[3];
  const int wave = tid >> 6, lane = tid & 63;
  const int h = hblk * 4 + wave;
  const us4* wrow = (const us4*)(Wvb + (size_t)h * DIM);
  float acc = 0.f;
#pragma unroll
  for (int t = 0; t < 4; ++t) {
    us4 v = wrow[t * 64 + lane];
    const int d0 = (t * 64 + lane) * 4;
    acc += ys[d0] * bfu2f(v[0]) + ys[d0 + 1] * bfu2f(v[1]) +
           ys[d0 + 2] * bfu2f(v[2]) + ys[d0 + 3] * bfu2f(v[3]);
  }
  for (int o = 32; o; o >>= 1) acc += __shfl_down(acc, o);
  if (lane == 0) item[b * DIM + h] = acc + su * bv[h];
}

// ---------------- broadcast item[b,:] over n ----------------
__global__ void bcast_kernel(const float* __restrict__ item, float* __restrict__ out) {
  const int b = blockIdx.y;
  const int n = blockIdx.x;
  const f32x4* src = (const f32x4*)(item + b * DIM);
  f32x4* dst = (f32x4*)(out + (((size_t)b * SEQ + n) << 10));
  dst[threadIdx.x] = src[threadIdx.x];
}

extern "C" void kernel_launch(void* const* d_in, const int* in_sizes, int n_in,
                              void* d_out, int out_size, void* d_ws, size_t ws_size,
                              hipStream_t stream) {
  const float* x    = (const float*)d_in[0];
  const float* ag   = (const float*)d_in[1];
  const float* vgr  = (const float*)d_in[2];
  const float* Wq   = (const float*)d_in[3];
  const float* bq   = (const float*)d_in[4];
  const float* Wk   = (const float*)d_in[5];
  const float* bk   = (const float*)d_in[6];
  const float* Wv   = (const float*)d_in[7];
  const float* bv   = (const float*)d_in[8];
  const int*   pos  = (const int*)d_in[9];
  float* out = (float*)d_out;

  char* ws = (char*)d_ws;
  size_t off = 0;
  auto alloc = [&](size_t bytes) { void* p = ws + off; off += (bytes + 255) & ~(size_t)255; return p; };
  const size_t BNH = (size_t)BATCH * SEQ * DIM;
  unsigned short* xb   = (unsigned short*)alloc(BNH * 2);
  unsigned short* zb   = (unsigned short*)alloc(BNH * 2);
  unsigned short* E    = (unsigned short*)alloc(BNH * 2);
  unsigned short* WqT  = (unsigned short*)alloc((size_t)DIM * DIM * 2);
  unsigned short* WkT  = (unsigned short*)alloc((size_t)DIM * DIM * 2);
  unsigned short* Wvb  = (unsigned short*)alloc((size_t)DIM * DIM * 2);
  unsigned short* Hb   = (unsigned short*)alloc((size_t)DIM * DIM * 2);
  float* w     = (float*)alloc((size_t)BATCH * SEQ * 4);
  float* denom = (float*)alloc((size_t)BATCH * SEQ * 4);
  float* av    = (float*)alloc((size_t)BATCH * SEQ * 4);
  float* cvv   = (float*)alloc((size_t)BATCH * SEQ * 4);
  float* t1    = (float*)alloc((size_t)DIM * 4);
  float* t2    = (float*)alloc((size_t)DIM * 4);
  float* zbias = (float*)alloc((size_t)DIM * 4);
  float* y     = (float*)alloc((size_t)BATCH * DIM * 4);
  float* item  = (float*)alloc((size_t)BATCH * DIM * 4);
  float* part1 = (float*)alloc((size_t)BATCH * 8 * SEQ * 4);
  float* part2 = (float*)alloc((size_t)BATCH * 8 * SEQ * 4);

  const float scale = 0.03125f;  // 1024^-0.5
  const int x4 = (int)(BNH / 4);

  // casts: x+Wv (one dispatch), Wq/Wk transposed
  cast_xw_kernel<<<(x4 + DIM * DIM / 4) / 256, 256, 0, stream>>>(x, Wv, xb, Wvb, x4);
  castT_kernel<<<dim3(16, 16, 2), 256, 0, stream>>>(Wq, Wk, WqT, WkT);

  // path-pool weights (+ denom/zbias zero-init)
  pathw_kernel<<<BATCH, 256, 0, stream>>>(pos, w, denom, zbias);

  // bias-fold vectors
  t12_kernel<<<dim3(256, 2), 256, 0, stream>>>(WqT, WkT, bq, bk, t1, t2);
  ac_kernel<<<256, 256, 0, stream>>>(xb, t1, t2, bq, bk, av, cvv);

  // H = scale * (Wk^T Wq)
  proj_gemm<<<dim3(8, 8), 256, 0, stream>>>(WkT, WqT, zbias, scale, Hb, DIM, DIM, DIM);

  // z = x @ H^T
  proj_gemm<<<dim3(128, 8), 256, 0, stream>>>(xb, Hb, zbias, 1.0f, zb,
                                              BATCH * SEQ, DIM, DIM);

  // E = exp(z x^T + a + c + graphs), denom += rowsums (two-tile pipelined)
  qk_exp_kernel<<<dim3(4, 8, BATCH), 256, 0, stream>>>(zb, xb, ag, vgr, av, cvv, E, denom);

  // u-partials: part1[b,nc,m] = sum_n (w/denom)[b,n] * E[b,n,m]
  wcolsum_part<<<dim3(4, 8, BATCH), 256, 0, stream>>>(E, w, denom, nullptr, part1);

  // y-partials with inline u-reduction: part2 = sum_m u[b,m] * x[b,m,d]
  wcolsum_part<<<dim3(4, 8, BATCH), 256, 0, stream>>>(xb, nullptr, nullptr, part1, part2);
  wcolsum_reduce<<<dim3(4, BATCH), 256, 0, stream>>>(part2, y);

  // item[b,h] = y@Wv^T + (sum u)*bv  (sum u from part1 inline)
  item_kernel<<<dim3(BATCH, 256), 256, 0, stream>>>(y, part1, Wvb, bv, item);

  // broadcast to [B,N,H]
  bcast_kernel<<<dim3(SEQ, BATCH), 256, 0, stream>>>(item, out);
}

// Round 6
// 232.087 us; speedup vs baseline: 1.1177x; 1.1177x over previous
//
#include <hip/hip_runtime.h>
#include <hip/hip_bf16.h>

#define BATCH 16
#define SEQ   1024
#define DIM   1024

typedef __attribute__((ext_vector_type(8))) short bf16x8;
typedef __attribute__((ext_vector_type(4))) float f32x4;
typedef __attribute__((ext_vector_type(4))) unsigned short us4;

__device__ __forceinline__ float bfu2f(unsigned short u) {
  union { unsigned int i; float f; } c; c.i = ((unsigned int)u) << 16; return c.f;
}
__device__ __forceinline__ unsigned short f2bfu(float f) {
  union { float f; unsigned int i; } c; c.f = f;
  return (unsigned short)((c.i + 0x7FFFu + ((c.i >> 16) & 1u)) >> 16);
}
__device__ __forceinline__ void async16(void* lds, const void* g) {
  __builtin_amdgcn_global_load_lds(
      (const __attribute__((address_space(1))) unsigned int*)g,
      (__attribute__((address_space(3))) unsigned int*)lds, 16, 0, 0);
}

// ---------------- cast fp32 -> bf16 for x and Wv in one dispatch ----------------
__global__ void cast_xw_kernel(const float* __restrict__ x, const float* __restrict__ Wv,
                               unsigned short* __restrict__ xb,
                               unsigned short* __restrict__ Wvb, int x4) {
  int i = blockIdx.x * blockDim.x + threadIdx.x;
  const float* in; unsigned short* out; int j;
  if (i < x4) { in = x; out = xb; j = i; }
  else { in = Wv; out = Wvb; j = i - x4; }
  f32x4 v = ((const f32x4*)in)[j];
  us4 o;
  o[0] = f2bfu(v[0]); o[1] = f2bfu(v[1]); o[2] = f2bfu(v[2]); o[3] = f2bfu(v[3]);
  ((us4*)out)[j] = o;
}

// ---------------- transpose-cast: out[i,h] = bf16(in[h,i]) for Wq, Wk ----------------
__global__ void castT_kernel(const float* __restrict__ Wq, const float* __restrict__ Wk,
                             unsigned short* __restrict__ WqT,
                             unsigned short* __restrict__ WkT) {
  const float* in = (blockIdx.z == 0) ? Wq : Wk;
  unsigned short* out = (blockIdx.z == 0) ? WqT : WkT;
  __shared__ float t[64][65];
  const int h0 = blockIdx.x * 64, i0 = blockIdx.y * 64;
  const int tid = threadIdx.x;
  const int sub = tid >> 4, c4 = tid & 15;
#pragma unroll
  for (int p = 0; p < 4; ++p) {
    const int row = p * 16 + sub;
    f32x4 v = *(const f32x4*)(in + (size_t)(h0 + row) * DIM + i0 + c4 * 4);
    t[row][c4 * 4 + 0] = v[0]; t[row][c4 * 4 + 1] = v[1];
    t[row][c4 * 4 + 2] = v[2]; t[row][c4 * 4 + 3] = v[3];
  }
  __syncthreads();
#pragma unroll
  for (int p = 0; p < 4; ++p) {
    const int orow = p * 16 + sub;
    us4 o;
    o[0] = f2bfu(t[c4 * 4 + 0][orow]);
    o[1] = f2bfu(t[c4 * 4 + 1][orow]);
    o[2] = f2bfu(t[c4 * 4 + 2][orow]);
    o[3] = f2bfu(t[c4 * 4 + 3][orow]);
    *(us4*)(out + (size_t)(i0 + orow) * DIM + h0 + c4 * 4) = o;
  }
}

// ---------------- t1 = WqT·bk, t2 = WkT·bq (row-dots) ----------------
__global__ void t12_kernel(const unsigned short* __restrict__ WqT,
                           const unsigned short* __restrict__ WkT,
                           const float* __restrict__ bq, const float* __restrict__ bk,
                           float* __restrict__ t1, float* __restrict__ t2) {
  const int y = blockIdx.y;
  const unsigned short* Wt = y ? WkT : WqT;
  const float* vec = y ? bq : bk;
  float* tout = y ? t2 : t1;
  const int wave = threadIdx.x >> 6, lane = threadIdx.x & 63;
  const int i = blockIdx.x * 4 + wave;
  const us4* wr = (const us4*)(Wt + (size_t)i * DIM);
  float s = 0.f;
#pragma unroll
  for (int t = 0; t < 4; ++t) {
    us4 w4 = wr[lane + 64 * t];
    f32x4 b4 = *(const f32x4*)(vec + (lane + 64 * t) * 4);
    s += bfu2f(w4[0]) * b4[0] + bfu2f(w4[1]) * b4[1] +
         bfu2f(w4[2]) * b4[2] + bfu2f(w4[3]) * b4[3];
  }
#pragma unroll
  for (int o = 32; o; o >>= 1) s += __shfl_down(s, o);
  if (lane == 0) tout[i] = s;
}

// ---------------- a[bn]=scale*(x_row·t1 + bq·bk); c[bn]=scale*(x_row·t2) ----------------
__global__ void ac_kernel(const unsigned short* __restrict__ xb,
                          const float* __restrict__ t1, const float* __restrict__ t2,
                          const float* __restrict__ bq, const float* __restrict__ bk,
                          float* __restrict__ a, float* __restrict__ c) {
  const float scale = 0.03125f;
  const int tid = threadIdx.x;
  const int wave = tid >> 6, lane = tid & 63;
  float dp = 0.f;
  for (int i = tid; i < DIM; i += 256) dp += bq[i] * bk[i];
#pragma unroll
  for (int o = 32; o; o >>= 1) dp += __shfl_down(dp, o);
  __shared__ float dred[4];
  if ((tid & 63) == 0) dred[tid >> 6] = dp;
  __syncthreads();
  const float d = dred[0] + dred[1] + dred[2] + dred[3];
  float t1r[16], t2r[16];
#pragma unroll
  for (int t = 0; t < 4; ++t) {
    f32x4 v1 = *(const f32x4*)(t1 + (lane + 64 * t) * 4);
    f32x4 v2 = *(const f32x4*)(t2 + (lane + 64 * t) * 4);
#pragma unroll
    for (int j = 0; j < 4; ++j) { t1r[t * 4 + j] = v1[j]; t2r[t * 4 + j] = v2[j]; }
  }
  for (int rr = 0; rr < 16; ++rr) {
    const int row = blockIdx.x * 64 + wave * 16 + rr;
    const us4* xr = (const us4*)(xb + (size_t)row * DIM);
    float sa = 0.f, sc = 0.f;
#pragma unroll
    for (int t = 0; t < 4; ++t) {
      us4 v = xr[lane + 64 * t];
#pragma unroll
      for (int j = 0; j < 4; ++j) {
        const float f = bfu2f(v[j]);
        sa += f * t1r[t * 4 + j];
        sc += f * t2r[t * 4 + j];
      }
    }
#pragma unroll
    for (int o = 32; o; o >>= 1) { sa += __shfl_down(sa, o); sc += __shfl_down(sc, o); }
    if (lane == 0) {
      a[row] = scale * (sa + d);
      c[row] = scale * sc;
    }
  }
}

// ---------------- path-pool weights w[b,j]; zero-inits denom (+zbias via block 0) ----------------
__global__ void pathw_kernel(const int* __restrict__ pos, float* __restrict__ w,
                             float* __restrict__ denom, float* __restrict__ zbias) {
  const int b = blockIdx.x;
  __shared__ int ps[SEQ];
  __shared__ int mcnt;
  const int tid = threadIdx.x;
  if (tid == 0) mcnt = 0;
  __syncthreads();
  if (b == 0)
    for (int i = tid; i < DIM; i += 256) zbias[i] = 0.f;
  for (int i = tid; i < SEQ; i += 256) {
    ps[i] = pos[b * SEQ + i];
    denom[b * SEQ + i] = 0.f;
  }
  __syncthreads();
  int c = 0;
  for (int i = tid; i < SEQ; i += 256) c += ps[i];
  for (int o = 32; o; o >>= 1) c += __shfl_down(c, o);
  if ((tid & 63) == 0) atomicAdd(&mcnt, c);
  __syncthreads();
  const float invM = 1.0f / (float)mcnt;
  for (int j = tid; j < SEQ; j += 256) {
    float a = 0.f;
#pragma unroll
    for (int di = -1; di <= 1; ++di) {
      int i = j + di;
      if (i < 0 || i >= SEQ) continue;
      if (!ps[i]) continue;
      int s, e;
      if (i < 2) { s = 0; e = (i == 0) ? 2 : 3; }
      else { s = (ps[i - 2] == 1) ? i : (i - 1); e = i + 2; if (e > SEQ) e = SEQ; }
      if (s <= j && j < e) a += 1.0f / (float)(e - s);
    }
    w[b * SEQ + j] = a * invM;
  }
}

// ---------------- bf16 NT GEMM: C = bf16((A @ W^T + bias)*alpha) ----------------
// XCD-aware swizzle: each XCD owns a contiguous m-range across all n-tiles
// (A panels fetched once chip-wide; B panel L2-resident).
__global__ void proj_gemm(const unsigned short* __restrict__ A,
                          const unsigned short* __restrict__ W,
                          const float* __restrict__ bias, float alpha,
                          unsigned short* __restrict__ C, int M, int N, int K)
{
  __shared__ __align__(16) char smem[16896];
  unsigned short* As = (unsigned short*)smem;
  unsigned short* Bs = (unsigned short*)(smem + 8192);
  float* Sl = (float*)smem;
  const int tid = threadIdx.x;
  const int wave = tid >> 6, lane = tid & 63;
  const int lr = lane & 15, lg = lane >> 4;
  const int wr = wave >> 1, wc = wave & 1;
  // bijective XCD swizzle (gridDim.x*gridDim.y % 8 == 0)
  const int flat = blockIdx.x + gridDim.x * blockIdx.y;
  const int q8 = (gridDim.x * gridDim.y) >> 3;
  const int t = (flat & 7) * q8 + (flat >> 3);
  const int m0 = (t / gridDim.y) * 128;        // n fastest within an XCD chunk
  const int n0 = (t % gridDim.y) * 128;
  const int off0 = tid * 16, off1 = 4096 + tid * 16;
  const int r0 = off0 >> 6, ke0 = (off0 >> 1) & 31;
  const int r1 = off1 >> 6, ke1 = (off1 >> 1) & 31;
  f32x4 acc[4][4] = {};
  for (int kk = 0; kk < K; kk += 32) {
    async16((char*)As + off0, A + (size_t)(m0 + r0) * K + kk + ke0);
    async16((char*)As + off1, A + (size_t)(m0 + r1) * K + kk + ke1);
    async16((char*)Bs + off0, W + (size_t)(n0 + r0) * K + kk + ke0);
    async16((char*)Bs + off1, W + (size_t)(n0 + r1) * K + kk + ke1);
    __syncthreads();
    bf16x8 af[4], bfv[4];
#pragma unroll
    for (int i = 0; i < 4; ++i) {
      af[i]  = *(const bf16x8*)((const char*)As + ((wr * 64 + i * 16 + lr) << 6) + (lg << 4));
      bfv[i] = *(const bf16x8*)((const char*)Bs + ((wc * 64 + i * 16 + lr) << 6) + (lg << 4));
    }
#pragma unroll
    for (int i = 0; i < 4; ++i)
#pragma unroll
      for (int j = 0; j < 4; ++j)
        acc[i][j] = __builtin_amdgcn_mfma_f32_16x16x32_bf16(af[i], bfv[j], acc[i][j], 0, 0, 0);
    __syncthreads();
  }
#pragma unroll
  for (int p = 0; p < 4; ++p) {
    __syncthreads();
    if (wr == (p >> 1)) {
      const int ibase = (p & 1) * 2;
#pragma unroll
      for (int ii = 0; ii < 2; ++ii) {
        const int i = ibase + ii;
#pragma unroll
        for (int j = 0; j < 4; ++j)
#pragma unroll
          for (int r = 0; r < 4; ++r)
            Sl[(ii * 16 + lg * 4 + r) * 132 + wc * 64 + j * 16 + lr] = acc[i][j][r];
      }
    }
    __syncthreads();
#pragma unroll
    for (int it = 0; it < 4; ++it) {
      const int v = tid + it * 256;
      const int lrow = v >> 5, c4 = v & 31;
      const int grow = m0 + p * 32 + lrow;
      const int col = n0 + c4 * 4;
      const f32x4 s4 = *(const f32x4*)(&Sl[lrow * 132 + c4 * 4]);
      const f32x4 b4 = *(const f32x4*)(bias + col);
      us4 o;
      o[0] = f2bfu((s4[0] + b4[0]) * alpha);
      o[1] = f2bfu((s4[1] + b4[1]) * alpha);
      o[2] = f2bfu((s4[2] + b4[2]) * alpha);
      o[3] = f2bfu((s4[3] + b4[3]) * alpha);
      *(us4*)(C + (size_t)grow * N + col) = o;
    }
  }
}

// ---------------- per-batch E = exp(z@x^T + a_n + c_m + atom + var), fused rowsum ----
// Single-tile (R4 structure): Sl overlaid on As/Bs, 32-row x 4 epilogue phases,
// 16.9 KB LDS -> 4 blocks/CU. XCD swizzle: XCD j owns batches {2j,2j+1}.
__global__ void qk_exp_kernel(const unsigned short* __restrict__ z,
                              const unsigned short* __restrict__ xb,
                              const float* __restrict__ ag,
                              const float* __restrict__ vg,
                              const float* __restrict__ av,
                              const float* __restrict__ cv,
                              unsigned short* __restrict__ E,
                              float* __restrict__ denom)
{
  __shared__ __align__(16) char smem[16896];
  unsigned short* As = (unsigned short*)smem;
  unsigned short* Bs = (unsigned short*)(smem + 8192);
  float* Sl = (float*)smem;
  // swizzle: flat 0..1023 -> tile; batch-contiguous per XCD, m fastest
  const int flat = blockIdx.x + 8 * blockIdx.y + 64 * blockIdx.z;
  const int t = (flat & 7) * 128 + (flat >> 3);
  const int b = t >> 6;
  const int m0 = (t & 7) * 128;
  const int n0 = ((t >> 3) & 7) * 128;
  const unsigned short* Aq = z + ((size_t)b << 20);
  const unsigned short* Bk = xb + ((size_t)b << 20);
  const int tid = threadIdx.x;
  const int wave = tid >> 6, lane = tid & 63;
  const int lr = lane & 15, lg = lane >> 4;
  const int wr = wave >> 1, wc = wave & 1;
  const int off0 = tid * 16, off1 = 4096 + tid * 16;
  const int r0 = off0 >> 6, ke0 = (off0 >> 1) & 31;
  const int r1 = off1 >> 6, ke1 = (off1 >> 1) & 31;
  f32x4 acc[4][4] = {};
  for (int kk = 0; kk < DIM; kk += 32) {
    async16((char*)As + off0, Aq + (size_t)(m0 + r0) * DIM + kk + ke0);
    async16((char*)As + off1, Aq + (size_t)(m0 + r1) * DIM + kk + ke1);
    async16((char*)Bs + off0, Bk + (size_t)(n0 + r0) * DIM + kk + ke0);
    async16((char*)Bs + off1, Bk + (size_t)(n0 + r1) * DIM + kk + ke1);
    __syncthreads();
    bf16x8 af[4], bfv[4];
#pragma unroll
    for (int i = 0; i < 4; ++i) {
      af[i]  = *(const bf16x8*)((const char*)As + ((wr * 64 + i * 16 + lr) << 6) + (lg << 4));
      bfv[i] = *(const bf16x8*)((const char*)Bs + ((wc * 64 + i * 16 + lr) << 6) + (lg << 4));
    }
#pragma unroll
    for (int i = 0; i < 4; ++i)
#pragma unroll
      for (int j = 0; j < 4; ++j)
        acc[i][j] = __builtin_amdgcn_mfma_f32_16x16x32_bf16(af[i], bfv[j], acc[i][j], 0, 0, 0);
    __syncthreads();
  }
  const float* agb = ag + ((size_t)b << 20);
  const float* vgb = vg + ((size_t)b << 20);
  unsigned short* Eb = E + ((size_t)b << 20);
  float* dnb = denom + b * SEQ;
  const float* avb = av + b * SEQ;
  const float* cvb = cv + b * SEQ;
#pragma unroll
  for (int p = 0; p < 4; ++p) {
    __syncthreads();
    if (wr == (p >> 1)) {
      const int ibase = (p & 1) * 2;
#pragma unroll
      for (int ii = 0; ii < 2; ++ii) {
        const int i = ibase + ii;
#pragma unroll
        for (int j = 0; j < 4; ++j)
#pragma unroll
          for (int r = 0; r < 4; ++r)
            Sl[(ii * 16 + lg * 4 + r) * 132 + wc * 64 + j * 16 + lr] = acc[i][j][r];
      }
    }
    __syncthreads();
#pragma unroll
    for (int it = 0; it < 4; ++it) {
      const int v = tid + it * 256;
      const int lrow = v >> 5, c4 = v & 31;
      const int grow = m0 + p * 32 + lrow;
      const size_t base = (size_t)grow * SEQ + n0 + c4 * 4;
      const f32x4 a4 = *(const f32x4*)(agb + base);
      const f32x4 g4 = *(const f32x4*)(vgb + base);
      const f32x4 c4v = *(const f32x4*)(cvb + n0 + c4 * 4);
      const float arow = avb[grow];
      const f32x4 s4 = *(const f32x4*)(&Sl[lrow * 132 + c4 * 4]);
      const float e0 = __expf(s4[0] + a4[0] + g4[0] + arow + c4v[0]);
      const float e1 = __expf(s4[1] + a4[1] + g4[1] + arow + c4v[1]);
      const float e2 = __expf(s4[2] + a4[2] + g4[2] + arow + c4v[2]);
      const float e3 = __expf(s4[3] + a4[3] + g4[3] + arow + c4v[3]);
      us4 o;
      o[0] = f2bfu(e0); o[1] = f2bfu(e1); o[2] = f2bfu(e2); o[3] = f2bfu(e3);
      *(us4*)(Eb + base) = o;
      float rs = e0 + e1 + e2 + e3;
#pragma unroll
      for (int o2 = 16; o2; o2 >>= 1) rs += __shfl_down(rs, o2, 32);
      if ((tid & 31) == 0) atomicAdd(&dnb[grow], rs);
    }
  }
}

// ---------------- weighted column sum: out[b,m] = sum_n c[b,n]*Mt[b,n,m]
// weights: if dv   -> c[n] = wv[n]/dv[n]
//          if pin  -> c[n] = sum_j pin[(b*8+j)*1024 + n]   (inline u-reduction)
__global__ void wcolsum_part(const unsigned short* __restrict__ Mt,
                             const float* __restrict__ wv,
                             const float* __restrict__ dv,
                             const float* __restrict__ pin,
                             float* __restrict__ part) {
  const int b = blockIdx.z;
  const int nc = blockIdx.y;
  const int m = blockIdx.x * 256 + threadIdx.x;
  __shared__ float c[128];
  const int tid = threadIdx.x;
  if (tid < 128) {
    const int n = nc * 128 + tid;
    float cvw;
    if (pin) {
      cvw = 0.f;
#pragma unroll
      for (int j = 0; j < 8; ++j) cvw += pin[(size_t)((b * 8 + j) << 10) + n];
    } else {
      cvw = wv[b * SEQ + n];
      if (dv) cvw /= dv[b * SEQ + n];
    }
    c[tid] = cvw;
  }
  __syncthreads();
  const unsigned short* p = Mt + ((size_t)b << 20) + ((size_t)(nc * 128) << 10) + m;
  float acc = 0.f;
#pragma unroll 8
  for (int n = 0; n < 128; ++n) acc += c[n] * bfu2f(p[(size_t)n << 10]);
  part[(size_t)((b * 8 + nc) << 10) + m] = acc;
}

__global__ void wcolsum_reduce(const float* __restrict__ part, float* __restrict__ out) {
  const int b = blockIdx.y;
  const int m = blockIdx.x * 256 + threadIdx.x;
  float s = 0.f;
#pragma unroll
  for (int nc = 0; nc < 8; ++nc) s += part[(size_t)((b * 8 + nc) << 10) + m];
  out[b * SEQ + m] = s;
}

// ---------------- item[b,h] = sum_d y[b,d]*Wv[h,d] + (sum u)*bv[h] ----------------
__global__ void item_kernel(const float* __restrict__ y, const float* __restrict__ part1,
                            const unsigned short* __restrict__ Wvb,
                            const float* __restrict__ bv, float* __restrict__ item) {
  const int b = blockIdx.x;
  const int hblk = blockIdx.y;
  __shared__ float ys[DIM];
  __shared__ float sred[4];
  const int tid = threadIdx.x;
  float part = 0.f;
  for (int i = tid; i < DIM; i += 256) ys[i] = y[b * DIM + i];
  for (int i = tid; i < 8 * SEQ; i += 256) part += part1[(size_t)(b * 8) * SEQ + i];
  for (int o = 32; o; o >>= 1) part += __shfl_down(part, o);
  if ((tid & 63) == 0) sred[tid >> 6] = part;
  __syncthreads();
  const float su = sred[0] + sred[1] + sred[2] + sred[3];
  const int wave = tid >> 6, lane = tid & 63;
  const int h = hblk * 4 + wave;
  const us4* wrow = (const us4*)(Wvb + (size_t)h * DIM);
  float acc = 0.f;
#pragma unroll
  for (int t = 0; t < 4; ++t) {
    us4 v = wrow[t * 64 + lane];
    const int d0 = (t * 64 + lane) * 4;
    acc += ys[d0] * bfu2f(v[0]) + ys[d0 + 1] * bfu2f(v[1]) +
           ys[d0 + 2] * bfu2f(v[2]) + ys[d0 + 3] * bfu2f(v[3]);
  }
  for (int o = 32; o; o >>= 1) acc += __shfl_down(acc, o);
  if (lane == 0) item[b * DIM + h] = acc + su * bv[h];
}

// ---------------- broadcast item[b,:] over n ----------------
__global__ void bcast_kernel(const float* __restrict__ item, float* __restrict__ out) {
  const int b = blockIdx.y;
  const int n = blockIdx.x;
  const f32x4* src = (const f32x4*)(item + b * DIM);
  f32x4* dst = (f32x4*)(out + (((size_t)b * SEQ + n) << 10));
  dst[threadIdx.x] = src[threadIdx.x];
}

extern "C" void kernel_launch(void* const* d_in, const int* in_sizes, int n_in,
                              void* d_out, int out_size, void* d_ws, size_t ws_size,
                              hipStream_t stream) {
  const float* x    = (const float*)d_in[0];
  const float* ag   = (const float*)d_in[1];
  const float* vgr  = (const float*)d_in[2];
  const float* Wq   = (const float*)d_in[3];
  const float* bq   = (const float*)d_in[4];
  const float* Wk   = (const float*)d_in[5];
  const float* bk   = (const float*)d_in[6];
  const float* Wv   = (const float*)d_in[7];
  const float* bv   = (const float*)d_in[8];
  const int*   pos  = (const int*)d_in[9];
  float* out = (float*)d_out;

  char* ws = (char*)d_ws;
  size_t off = 0;
  auto alloc = [&](size_t bytes) { void* p = ws + off; off += (bytes + 255) & ~(size_t)255; return p; };
  const size_t BNH = (size_t)BATCH * SEQ * DIM;
  unsigned short* xb   = (unsigned short*)alloc(BNH * 2);
  unsigned short* zb   = (unsigned short*)alloc(BNH * 2);
  unsigned short* E    = (unsigned short*)alloc(BNH * 2);
  unsigned short* WqT  = (unsigned short*)alloc((size_t)DIM * DIM * 2);
  unsigned short* WkT  = (unsigned short*)alloc((size_t)DIM * DIM * 2);
  unsigned short* Wvb  = (unsigned short*)alloc((size_t)DIM * DIM * 2);
  unsigned short* Hb   = (unsigned short*)alloc((size_t)DIM * DIM * 2);
  float* w     = (float*)alloc((size_t)BATCH * SEQ * 4);
  float* denom = (float*)alloc((size_t)BATCH * SEQ * 4);
  float* av    = (float*)alloc((size_t)BATCH * SEQ * 4);
  float* cvv   = (float*)alloc((size_t)BATCH * SEQ * 4);
  float* t1    = (float*)alloc((size_t)DIM * 4);
  float* t2    = (float*)alloc((size_t)DIM * 4);
  float* zbias = (float*)alloc((size_t)DIM * 4);
  float* y     = (float*)alloc((size_t)BATCH * DIM * 4);
  float* item  = (float*)alloc((size_t)BATCH * DIM * 4);
  float* part1 = (float*)alloc((size_t)BATCH * 8 * SEQ * 4);
  float* part2 = (float*)alloc((size_t)BATCH * 8 * SEQ * 4);

  const float scale = 0.03125f;  // 1024^-0.5
  const int x4 = (int)(BNH / 4);

  // casts: x+Wv (one dispatch), Wq/Wk transposed
  cast_xw_kernel<<<(x4 + DIM * DIM / 4) / 256, 256, 0, stream>>>(x, Wv, xb, Wvb, x4);
  castT_kernel<<<dim3(16, 16, 2), 256, 0, stream>>>(Wq, Wk, WqT, WkT);

  // path-pool weights (+ denom/zbias zero-init)
  pathw_kernel<<<BATCH, 256, 0, stream>>>(pos, w, denom, zbias);

  // bias-fold vectors
  t12_kernel<<<dim3(256, 2), 256, 0, stream>>>(WqT, WkT, bq, bk, t1, t2);
  ac_kernel<<<256, 256, 0, stream>>>(xb, t1, t2, bq, bk, av, cvv);

  // H = scale * (Wk^T Wq)
  proj_gemm<<<dim3(8, 8), 256, 0, stream>>>(WkT, WqT, zbias, scale, Hb, DIM, DIM, DIM);

  // z = x @ H^T
  proj_gemm<<<dim3(128, 8), 256, 0, stream>>>(xb, Hb, zbias, 1.0f, zb,
                                              BATCH * SEQ, DIM, DIM);

  // E = exp(z x^T + a + c + graphs), denom += rowsums
  qk_exp_kernel<<<dim3(8, 8, BATCH), 256, 0, stream>>>(zb, xb, ag, vgr, av, cvv, E, denom);

  // u-partials: part1[b,nc,m] = sum_n (w/denom)[b,n] * E[b,n,m]
  wcolsum_part<<<dim3(4, 8, BATCH), 256, 0, stream>>>(E, w, denom, nullptr, part1);

  // y-partials with inline u-reduction: part2 = sum_m u[b,m] * x[b,m,d]
  wcolsum_part<<<dim3(4, 8, BATCH), 256, 0, stream>>>(xb, nullptr, nullptr, part1, part2);
  wcolsum_reduce<<<dim3(4, BATCH), 256, 0, stream>>>(part2, y);

  // item[b,h] = y@Wv^T + (sum u)*bv  (sum u from part1 inline)
  item_kernel<<<dim3(BATCH, 256), 256, 0, stream>>>(y, part1, Wvb, bv, item);

  // broadcast to [B,N,H]
  bcast_kernel<<<dim3(SEQ, BATCH), 256, 0, stream>>>(item, out);
}

// Round 7
// 222.784 us; speedup vs baseline: 1.1644x; 1.0418x over previous
//
#include <hip/hip_runtime.h>
#include <hip/hip_bf16.h>

#define BATCH 16
#define SEQ   1024
#define DIM   1024

typedef __attribute__((ext_vector_type(8))) short bf16x8;
typedef __attribute__((ext_vector_type(4))) float f32x4;
typedef __attribute__((ext_vector_type(4))) unsigned short us4;

__device__ __forceinline__ float bfu2f(unsigned short u) {
  union { unsigned int i; float f; } c; c.i = ((unsigned int)u) << 16; return c.f;
}
__device__ __forceinline__ unsigned short f2bfu(float f) {
  union { float f; unsigned int i; } c; c.f = f;
  return (unsigned short)((c.i + 0x7FFFu + ((c.i >> 16) & 1u)) >> 16);
}
__device__ __forceinline__ void async16(void* lds, const void* g) {
  __builtin_amdgcn_global_load_lds(
      (const __attribute__((address_space(1))) unsigned int*)g,
      (__attribute__((address_space(3))) unsigned int*)lds, 16, 0, 0);
}

// ---------------- cast fp32 -> bf16 for x and Wv in one dispatch ----------------
__global__ void cast_xw_kernel(const float* __restrict__ x, const float* __restrict__ Wv,
                               unsigned short* __restrict__ xb,
                               unsigned short* __restrict__ Wvb, int x4) {
  int i = blockIdx.x * blockDim.x + threadIdx.x;
  const float* in; unsigned short* out; int j;
  if (i < x4) { in = x; out = xb; j = i; }
  else { in = Wv; out = Wvb; j = i - x4; }
  f32x4 v = ((const f32x4*)in)[j];
  us4 o;
  o[0] = f2bfu(v[0]); o[1] = f2bfu(v[1]); o[2] = f2bfu(v[2]); o[3] = f2bfu(v[3]);
  ((us4*)out)[j] = o;
}

// ---------------- transpose-cast: out[i,h] = bf16(in[h,i]) for Wq, Wk ----------------
__global__ void castT_kernel(const float* __restrict__ Wq, const float* __restrict__ Wk,
                             unsigned short* __restrict__ WqT,
                             unsigned short* __restrict__ WkT) {
  const float* in = (blockIdx.z == 0) ? Wq : Wk;
  unsigned short* out = (blockIdx.z == 0) ? WqT : WkT;
  __shared__ float t[64][65];
  const int h0 = blockIdx.x * 64, i0 = blockIdx.y * 64;
  const int tid = threadIdx.x;
  const int sub = tid >> 4, c4 = tid & 15;
#pragma unroll
  for (int p = 0; p < 4; ++p) {
    const int row = p * 16 + sub;
    f32x4 v = *(const f32x4*)(in + (size_t)(h0 + row) * DIM + i0 + c4 * 4);
    t[row][c4 * 4 + 0] = v[0]; t[row][c4 * 4 + 1] = v[1];
    t[row][c4 * 4 + 2] = v[2]; t[row][c4 * 4 + 3] = v[3];
  }
  __syncthreads();
#pragma unroll
  for (int p = 0; p < 4; ++p) {
    const int orow = p * 16 + sub;
    us4 o;
    o[0] = f2bfu(t[c4 * 4 + 0][orow]);
    o[1] = f2bfu(t[c4 * 4 + 1][orow]);
    o[2] = f2bfu(t[c4 * 4 + 2][orow]);
    o[3] = f2bfu(t[c4 * 4 + 3][orow]);
    *(us4*)(out + (size_t)(i0 + orow) * DIM + h0 + c4 * 4) = o;
  }
}

// ---------------- t1 = WqT·bk, t2 = WkT·bq (row-dots) ----------------
__global__ void t12_kernel(const unsigned short* __restrict__ WqT,
                           const unsigned short* __restrict__ WkT,
                           const float* __restrict__ bq, const float* __restrict__ bk,
                           float* __restrict__ t1, float* __restrict__ t2) {
  const int y = blockIdx.y;
  const unsigned short* Wt = y ? WkT : WqT;
  const float* vec = y ? bq : bk;
  float* tout = y ? t2 : t1;
  const int wave = threadIdx.x >> 6, lane = threadIdx.x & 63;
  const int i = blockIdx.x * 4 + wave;
  const us4* wr = (const us4*)(Wt + (size_t)i * DIM);
  float s = 0.f;
#pragma unroll
  for (int t = 0; t < 4; ++t) {
    us4 w4 = wr[lane + 64 * t];
    f32x4 b4 = *(const f32x4*)(vec + (lane + 64 * t) * 4);
    s += bfu2f(w4[0]) * b4[0] + bfu2f(w4[1]) * b4[1] +
         bfu2f(w4[2]) * b4[2] + bfu2f(w4[3]) * b4[3];
  }
#pragma unroll
  for (int o = 32; o; o >>= 1) s += __shfl_down(s, o);
  if (lane == 0) tout[i] = s;
}

// ---------------- a[bn]=scale*(x_row·t1 + bq·bk); c[bn]=scale*(x_row·t2) ----------------
__global__ void ac_kernel(const unsigned short* __restrict__ xb,
                          const float* __restrict__ t1, const float* __restrict__ t2,
                          const float* __restrict__ bq, const float* __restrict__ bk,
                          float* __restrict__ a, float* __restrict__ c) {
  const float scale = 0.03125f;
  const int tid = threadIdx.x;
  const int wave = tid >> 6, lane = tid & 63;
  float dp = 0.f;
  for (int i = tid; i < DIM; i += 256) dp += bq[i] * bk[i];
#pragma unroll
  for (int o = 32; o; o >>= 1) dp += __shfl_down(dp, o);
  __shared__ float dred[4];
  if ((tid & 63) == 0) dred[tid >> 6] = dp;
  __syncthreads();
  const float d = dred[0] + dred[1] + dred[2] + dred[3];
  float t1r[16], t2r[16];
#pragma unroll
  for (int t = 0; t < 4; ++t) {
    f32x4 v1 = *(const f32x4*)(t1 + (lane + 64 * t) * 4);
    f32x4 v2 = *(const f32x4*)(t2 + (lane + 64 * t) * 4);
#pragma unroll
    for (int j = 0; j < 4; ++j) { t1r[t * 4 + j] = v1[j]; t2r[t * 4 + j] = v2[j]; }
  }
  for (int rr = 0; rr < 16; ++rr) {
    const int row = blockIdx.x * 64 + wave * 16 + rr;
    const us4* xr = (const us4*)(xb + (size_t)row * DIM);
    float sa = 0.f, sc = 0.f;
#pragma unroll
    for (int t = 0; t < 4; ++t) {
      us4 v = xr[lane + 64 * t];
#pragma unroll
      for (int j = 0; j < 4; ++j) {
        const float f = bfu2f(v[j]);
        sa += f * t1r[t * 4 + j];
        sc += f * t2r[t * 4 + j];
      }
    }
#pragma unroll
    for (int o = 32; o; o >>= 1) { sa += __shfl_down(sa, o); sc += __shfl_down(sc, o); }
    if (lane == 0) {
      a[row] = scale * (sa + d);
      c[row] = scale * sc;
    }
  }
}

// ---------------- path-pool weights w[b,j]; zero-inits denom (+zbias via block 0) ----------------
__global__ void pathw_kernel(const int* __restrict__ pos, float* __restrict__ w,
                             float* __restrict__ denom, float* __restrict__ zbias) {
  const int b = blockIdx.x;
  __shared__ int ps[SEQ];
  __shared__ int mcnt;
  const int tid = threadIdx.x;
  if (tid == 0) mcnt = 0;
  __syncthreads();
  if (b == 0)
    for (int i = tid; i < DIM; i += 256) zbias[i] = 0.f;
  for (int i = tid; i < SEQ; i += 256) {
    ps[i] = pos[b * SEQ + i];
    denom[b * SEQ + i] = 0.f;
  }
  __syncthreads();
  int c = 0;
  for (int i = tid; i < SEQ; i += 256) c += ps[i];
  for (int o = 32; o; o >>= 1) c += __shfl_down(c, o);
  if ((tid & 63) == 0) atomicAdd(&mcnt, c);
  __syncthreads();
  const float invM = 1.0f / (float)mcnt;
  for (int j = tid; j < SEQ; j += 256) {
    float a = 0.f;
#pragma unroll
    for (int di = -1; di <= 1; ++di) {
      int i = j + di;
      if (i < 0 || i >= SEQ) continue;
      if (!ps[i]) continue;
      int s, e;
      if (i < 2) { s = 0; e = (i == 0) ? 2 : 3; }
      else { s = (ps[i - 2] == 1) ? i : (i - 1); e = i + 2; if (e > SEQ) e = SEQ; }
      if (s <= j && j < e) a += 1.0f / (float)(e - s);
    }
    w[b * SEQ + j] = a * invM;
  }
}

// ---------------- bf16 NT GEMM: C = bf16((A @ W^T + bias)*alpha) ----------------
__global__ void proj_gemm(const unsigned short* __restrict__ A,
                          const unsigned short* __restrict__ W,
                          const float* __restrict__ bias, float alpha,
                          unsigned short* __restrict__ C, int M, int N, int K)
{
  __shared__ __align__(16) char smem[16896];
  unsigned short* As = (unsigned short*)smem;
  unsigned short* Bs = (unsigned short*)(smem + 8192);
  float* Sl = (float*)smem;
  const int tid = threadIdx.x;
  const int wave = tid >> 6, lane = tid & 63;
  const int lr = lane & 15, lg = lane >> 4;
  const int wr = wave >> 1, wc = wave & 1;
  const int flat = blockIdx.x + gridDim.x * blockIdx.y;
  const int q8 = (gridDim.x * gridDim.y) >> 3;
  const int t = (flat & 7) * q8 + (flat >> 3);
  const int m0 = (t / gridDim.y) * 128;
  const int n0 = (t % gridDim.y) * 128;
  const int off0 = tid * 16, off1 = 4096 + tid * 16;
  const int r0 = off0 >> 6, ke0 = (off0 >> 1) & 31;
  const int r1 = off1 >> 6, ke1 = (off1 >> 1) & 31;
  f32x4 acc[4][4] = {};
  for (int kk = 0; kk < K; kk += 32) {
    async16((char*)As + off0, A + (size_t)(m0 + r0) * K + kk + ke0);
    async16((char*)As + off1, A + (size_t)(m0 + r1) * K + kk + ke1);
    async16((char*)Bs + off0, W + (size_t)(n0 + r0) * K + kk + ke0);
    async16((char*)Bs + off1, W + (size_t)(n0 + r1) * K + kk + ke1);
    __syncthreads();
    bf16x8 af[4], bfv[4];
#pragma unroll
    for (int i = 0; i < 4; ++i) {
      af[i]  = *(const bf16x8*)((const char*)As + ((wr * 64 + i * 16 + lr) << 6) + (lg << 4));
      bfv[i] = *(const bf16x8*)((const char*)Bs + ((wc * 64 + i * 16 + lr) << 6) + (lg << 4));
    }
#pragma unroll
    for (int i = 0; i < 4; ++i)
#pragma unroll
      for (int j = 0; j < 4; ++j)
        acc[i][j] = __builtin_amdgcn_mfma_f32_16x16x32_bf16(af[i], bfv[j], acc[i][j], 0, 0, 0);
    __syncthreads();
  }
#pragma unroll
  for (int p = 0; p < 4; ++p) {
    __syncthreads();
    if (wr == (p >> 1)) {
      const int ibase = (p & 1) * 2;
#pragma unroll
      for (int ii = 0; ii < 2; ++ii) {
        const int i = ibase + ii;
#pragma unroll
        for (int j = 0; j < 4; ++j)
#pragma unroll
          for (int r = 0; r < 4; ++r)
            Sl[(ii * 16 + lg * 4 + r) * 132 + wc * 64 + j * 16 + lr] = acc[i][j][r];
      }
    }
    __syncthreads();
#pragma unroll
    for (int it = 0; it < 4; ++it) {
      const int v = tid + it * 256;
      const int lrow = v >> 5, c4 = v & 31;
      const int grow = m0 + p * 32 + lrow;
      const int col = n0 + c4 * 4;
      const f32x4 s4 = *(const f32x4*)(&Sl[lrow * 132 + c4 * 4]);
      const f32x4 b4 = *(const f32x4*)(bias + col);
      us4 o;
      o[0] = f2bfu((s4[0] + b4[0]) * alpha);
      o[1] = f2bfu((s4[1] + b4[1]) * alpha);
      o[2] = f2bfu((s4[2] + b4[2]) * alpha);
      o[3] = f2bfu((s4[3] + b4[3]) * alpha);
      *(us4*)(C + (size_t)grow * N + col) = o;
    }
  }
}

// ---------------- per-batch E = exp(z@x^T + a_n + c_m + atom + var), fused rowsum ----
// Single restage of the whole 128x128 acc tile as bf16 into LDS (2 barriers),
// then 16 epilogue chunks in 4 batches of 4 with all graph loads issued up-front
// (4x memory-level parallelism). XCD swizzle: XCD j owns batches {2j,2j+1}.
__global__ void qk_exp_kernel(const unsigned short* __restrict__ z,
                              const unsigned short* __restrict__ xb,
                              const float* __restrict__ ag,
                              const float* __restrict__ vg,
                              const float* __restrict__ av,
                              const float* __restrict__ cv,
                              unsigned short* __restrict__ E,
                              float* __restrict__ denom)
{
  __shared__ __align__(16) char smem[33792];  // max(As+Bs=16384, Slb=128*132*2)
  unsigned short* As = (unsigned short*)smem;
  unsigned short* Bs = (unsigned short*)(smem + 8192);
  unsigned short* Slb = (unsigned short*)smem;
  const int flat = blockIdx.x + 8 * blockIdx.y + 64 * blockIdx.z;
  const int t = (flat & 7) * 128 + (flat >> 3);
  const int b = t >> 6;
  const int m0 = (t & 7) * 128;
  const int n0 = ((t >> 3) & 7) * 128;
  const unsigned short* Aq = z + ((size_t)b << 20);
  const unsigned short* Bk = xb + ((size_t)b << 20);
  const int tid = threadIdx.x;
  const int wave = tid >> 6, lane = tid & 63;
  const int lr = lane & 15, lg = lane >> 4;
  const int wr = wave >> 1, wc = wave & 1;
  const int off0 = tid * 16, off1 = 4096 + tid * 16;
  const int r0 = off0 >> 6, ke0 = (off0 >> 1) & 31;
  const int r1 = off1 >> 6, ke1 = (off1 >> 1) & 31;
  f32x4 acc[4][4] = {};
  for (int kk = 0; kk < DIM; kk += 32) {
    async16((char*)As + off0, Aq + (size_t)(m0 + r0) * DIM + kk + ke0);
    async16((char*)As + off1, Aq + (size_t)(m0 + r1) * DIM + kk + ke1);
    async16((char*)Bs + off0, Bk + (size_t)(n0 + r0) * DIM + kk + ke0);
    async16((char*)Bs + off1, Bk + (size_t)(n0 + r1) * DIM + kk + ke1);
    __syncthreads();
    bf16x8 af[4], bfv[4];
#pragma unroll
    for (int i = 0; i < 4; ++i) {
      af[i]  = *(const bf16x8*)((const char*)As + ((wr * 64 + i * 16 + lr) << 6) + (lg << 4));
      bfv[i] = *(const bf16x8*)((const char*)Bs + ((wc * 64 + i * 16 + lr) << 6) + (lg << 4));
    }
#pragma unroll
    for (int i = 0; i < 4; ++i)
#pragma unroll
      for (int j = 0; j < 4; ++j)
        acc[i][j] = __builtin_amdgcn_mfma_f32_16x16x32_bf16(af[i], bfv[j], acc[i][j], 0, 0, 0);
    __syncthreads();
  }
  // ---- single full-tile restage as bf16 (S sigma ~0.33 -> bf16 error negligible) ----
#pragma unroll
  for (int i = 0; i < 4; ++i)
#pragma unroll
    for (int j = 0; j < 4; ++j)
#pragma unroll
      for (int r = 0; r < 4; ++r)
        Slb[(wr * 64 + i * 16 + lg * 4 + r) * 132 + wc * 64 + j * 16 + lr] =
            f2bfu(acc[i][j][r]);
  __syncthreads();
  const float* agb = ag + ((size_t)b << 20);
  const float* vgb = vg + ((size_t)b << 20);
  unsigned short* Eb = E + ((size_t)b << 20);
  float* dnb = denom + b * SEQ;
  const float* avb = av + b * SEQ;
  const float* cvb = cv + b * SEQ;
  // ---- epilogue: 16 chunks, batches of 4, loads issued up-front ----
#pragma unroll
  for (int bt = 0; bt < 4; ++bt) {
    f32x4 a4[4], g4[4];
    int lrow[4];
    size_t basev[4];
#pragma unroll
    for (int q = 0; q < 4; ++q) {
      const int v = tid + (bt * 4 + q) * 256;     // 0..4095 = 128 rows x 32 col-quads
      lrow[q] = v >> 5;
      const int c4 = v & 31;
      basev[q] = (size_t)(m0 + lrow[q]) * SEQ + n0 + c4 * 4;
      a4[q] = *(const f32x4*)(agb + basev[q]);
      g4[q] = *(const f32x4*)(vgb + basev[q]);
    }
#pragma unroll
    for (int q = 0; q < 4; ++q) {
      const int v = tid + (bt * 4 + q) * 256;
      const int c4 = v & 31;
      const f32x4 c4v = *(const f32x4*)(cvb + n0 + c4 * 4);
      const float arow = avb[m0 + lrow[q]];
      const us4 sv = *(const us4*)(&Slb[lrow[q] * 132 + c4 * 4]);
      const float e0 = __expf(bfu2f(sv[0]) + a4[q][0] + g4[q][0] + arow + c4v[0]);
      const float e1 = __expf(bfu2f(sv[1]) + a4[q][1] + g4[q][1] + arow + c4v[1]);
      const float e2 = __expf(bfu2f(sv[2]) + a4[q][2] + g4[q][2] + arow + c4v[2]);
      const float e3 = __expf(bfu2f(sv[3]) + a4[q][3] + g4[q][3] + arow + c4v[3]);
      us4 o;
      o[0] = f2bfu(e0); o[1] = f2bfu(e1); o[2] = f2bfu(e2); o[3] = f2bfu(e3);
      *(us4*)(Eb + basev[q]) = o;
      float rs = e0 + e1 + e2 + e3;
#pragma unroll
      for (int o2 = 16; o2; o2 >>= 1) rs += __shfl_down(rs, o2, 32);
      if ((tid & 31) == 0) atomicAdd(&dnb[m0 + lrow[q]], rs);
    }
  }
}

// ---------------- weighted column partial: part[b][nc][m] = sum_{n in chunk} c_n*Mt[b,n,m]
// Thread owns 4 consecutive m (us4 loads, 8B -> 4x MLP vs scalar u16).
// weights: dv!=null -> c = wv/dv ; else c = wv.
__global__ void wcol_kernel(const unsigned short* __restrict__ Mt,
                            const float* __restrict__ wv,
                            const float* __restrict__ dv,
                            float* __restrict__ part) {
  const int nc = blockIdx.x;           // 16 chunks of 64 n
  const int b = blockIdx.y;
  const int tid = threadIdx.x;
  __shared__ float c[64];
  if (tid < 64) {
    const int n = nc * 64 + tid;
    float cvw = wv[b * SEQ + n];
    if (dv) cvw /= dv[b * SEQ + n];
    c[tid] = cvw;
  }
  __syncthreads();
  const unsigned short* p = Mt + ((size_t)b << 20) + ((size_t)(nc * 64) << 10) + tid * 4;
  f32x4 acc = {0.f, 0.f, 0.f, 0.f};
#pragma unroll 8
  for (int n = 0; n < 64; ++n) {
    const us4 v = *(const us4*)(p + ((size_t)n << 10));
    const float cn = c[n];
    acc[0] += cn * bfu2f(v[0]); acc[1] += cn * bfu2f(v[1]);
    acc[2] += cn * bfu2f(v[2]); acc[3] += cn * bfu2f(v[3]);
  }
  *(f32x4*)(part + (size_t)((b * 16 + nc) << 10) + tid * 4) = acc;
}

// ---------------- reduce part -> vec[b][m]; optionally also su[b] = sum_m vec ----------------
__global__ void wred_kernel(const float* __restrict__ part, float* __restrict__ vec,
                            float* __restrict__ su) {
  const int b = blockIdx.x;
  const int tid = threadIdx.x;
  f32x4 s = {0.f, 0.f, 0.f, 0.f};
#pragma unroll
  for (int nc = 0; nc < 16; ++nc) {
    const f32x4 v = *(const f32x4*)(part + (size_t)((b * 16 + nc) << 10) + tid * 4);
    s[0] += v[0]; s[1] += v[1]; s[2] += v[2]; s[3] += v[3];
  }
  *(f32x4*)(vec + b * SEQ + tid * 4) = s;
  if (su) {
    float ts = s[0] + s[1] + s[2] + s[3];
#pragma unroll
    for (int o = 32; o; o >>= 1) ts += __shfl_down(ts, o);
    __shared__ float red[4];
    if ((tid & 63) == 0) red[tid >> 6] = ts;
    __syncthreads();
    if (tid == 0) su[b] = red[0] + red[1] + red[2] + red[3];
  }
}

// ---------------- item[b,h] = sum_d y[b,d]*Wv[h,d] + su[b]*bv[h] ----------------
__global__ void item_kernel(const float* __restrict__ y, const float* __restrict__ su,
                            const unsigned short* __restrict__ Wvb,
                            const float* __restrict__ bv, float* __restrict__ item) {
  const int b = blockIdx.x;
  const int hblk = blockIdx.y;
  __shared__ float ys[DIM];
  const int tid = threadIdx.x;
  for (int i = tid; i < DIM; i += 256) ys[i] = y[b * DIM + i];
  __syncthreads();
  const float sub = su[b];
  const int wave = tid >> 6, lane = tid & 63;
  const int h = hblk * 4 + wave;
  const us4* wrow = (const us4*)(Wvb + (size_t)h * DIM);
  float acc = 0.f;
#pragma unroll
  for (int t = 0; t < 4; ++t) {
    us4 v = wrow[t * 64 + lane];
    const int d0 = (t * 64 + lane) * 4;
    acc += ys[d0] * bfu2f(v[0]) + ys[d0 + 1] * bfu2f(v[1]) +
           ys[d0 + 2] * bfu2f(v[2]) + ys[d0 + 3] * bfu2f(v[3]);
  }
  for (int o = 32; o; o >>= 1) acc += __shfl_down(acc, o);
  if (lane == 0) item[b * DIM + h] = acc + sub * bv[h];
}

// ---------------- broadcast item[b,:] over n ----------------
__global__ void bcast_kernel(const float* __restrict__ item, float* __restrict__ out) {
  const int b = blockIdx.y;
  const int n = blockIdx.x;
  const f32x4* src = (const f32x4*)(item + b * DIM);
  f32x4* dst = (f32x4*)(out + (((size_t)b * SEQ + n) << 10));
  dst[threadIdx.x] = src[threadIdx.x];
}

extern "C" void kernel_launch(void* const* d_in, const int* in_sizes, int n_in,
                              void* d_out, int out_size, void* d_ws, size_t ws_size,
                              hipStream_t stream) {
  const float* x    = (const float*)d_in[0];
  const float* ag   = (const float*)d_in[1];
  const float* vgr  = (const float*)d_in[2];
  const float* Wq   = (const float*)d_in[3];
  const float* bq   = (const float*)d_in[4];
  const float* Wk   = (const float*)d_in[5];
  const float* bk   = (const float*)d_in[6];
  const float* Wv   = (const float*)d_in[7];
  const float* bv   = (const float*)d_in[8];
  const int*   pos  = (const int*)d_in[9];
  float* out = (float*)d_out;

  char* ws = (char*)d_ws;
  size_t off = 0;
  auto alloc = [&](size_t bytes) { void* p = ws + off; off += (bytes + 255) & ~(size_t)255; return p; };
  const size_t BNH = (size_t)BATCH * SEQ * DIM;
  unsigned short* xb   = (unsigned short*)alloc(BNH * 2);
  unsigned short* zb   = (unsigned short*)alloc(BNH * 2);
  unsigned short* E    = (unsigned short*)alloc(BNH * 2);
  unsigned short* WqT  = (unsigned short*)alloc((size_t)DIM * DIM * 2);
  unsigned short* WkT  = (unsigned short*)alloc((size_t)DIM * DIM * 2);
  unsigned short* Wvb  = (unsigned short*)alloc((size_t)DIM * DIM * 2);
  unsigned short* Hb   = (unsigned short*)alloc((size_t)DIM * DIM * 2);
  float* w     = (float*)alloc((size_t)BATCH * SEQ * 4);
  float* denom = (float*)alloc((size_t)BATCH * SEQ * 4);
  float* u     = (float*)alloc((size_t)BATCH * SEQ * 4);
  float* av    = (float*)alloc((size_t)BATCH * SEQ * 4);
  float* cvv   = (float*)alloc((size_t)BATCH * SEQ * 4);
  float* t1    = (float*)alloc((size_t)DIM * 4);
  float* t2    = (float*)alloc((size_t)DIM * 4);
  float* zbias = (float*)alloc((size_t)DIM * 4);
  float* y     = (float*)alloc((size_t)BATCH * DIM * 4);
  float* su    = (float*)alloc((size_t)BATCH * 4);
  float* item  = (float*)alloc((size_t)BATCH * DIM * 4);
  float* part  = (float*)alloc((size_t)BATCH * 16 * SEQ * 4);

  const float scale = 0.03125f;  // 1024^-0.5
  const int x4 = (int)(BNH / 4);

  // casts: x+Wv (one dispatch), Wq/Wk transposed
  cast_xw_kernel<<<(x4 + DIM * DIM / 4) / 256, 256, 0, stream>>>(x, Wv, xb, Wvb, x4);
  castT_kernel<<<dim3(16, 16, 2), 256, 0, stream>>>(Wq, Wk, WqT, WkT);

  // path-pool weights (+ denom/zbias zero-init)
  pathw_kernel<<<BATCH, 256, 0, stream>>>(pos, w, denom, zbias);

  // bias-fold vectors
  t12_kernel<<<dim3(256, 2), 256, 0, stream>>>(WqT, WkT, bq, bk, t1, t2);
  ac_kernel<<<256, 256, 0, stream>>>(xb, t1, t2, bq, bk, av, cvv);

  // H = scale * (Wk^T Wq)
  proj_gemm<<<dim3(8, 8), 256, 0, stream>>>(WkT, WqT, zbias, scale, Hb, DIM, DIM, DIM);

  // z = x @ H^T
  proj_gemm<<<dim3(128, 8), 256, 0, stream>>>(xb, Hb, zbias, 1.0f, zb,
                                              BATCH * SEQ, DIM, DIM);

  // E = exp(z x^T + a + c + graphs), denom += rowsums
  qk_exp_kernel<<<dim3(8, 8, BATCH), 256, 0, stream>>>(zb, xb, ag, vgr, av, cvv, E, denom);

  // u[b,m] = sum_n (w/denom)[b,n] * E[b,n,m]; su[b] = sum_m u
  wcol_kernel<<<dim3(16, BATCH), 256, 0, stream>>>(E, w, denom, part);
  wred_kernel<<<BATCH, 256, 0, stream>>>(part, u, su);

  // y[b,d] = sum_m u[b,m] * x[b,m,d]
  wcol_kernel<<<dim3(16, BATCH), 256, 0, stream>>>(xb, u, nullptr, part);
  wred_kernel<<<BATCH, 256, 0, stream>>>(part, y, nullptr);

  // item[b,h] = y@Wv^T + su*bv
  item_kernel<<<dim3(BATCH, 256), 256, 0, stream>>>(y, su, Wvb, bv, item);

  // broadcast to [B,N,H]
  bcast_kernel<<<dim3(SEQ, BATCH), 256, 0, stream>>>(item, out);
}

// Round 8
// 216.859 us; speedup vs baseline: 1.1962x; 1.0273x over previous
//
#include <hip/hip_runtime.h>
#include <hip/hip_bf16.h>

#define BATCH 16
#define SEQ   1024
#define DIM   1024

typedef __attribute__((ext_vector_type(8))) short bf16x8;
typedef __attribute__((ext_vector_type(4))) float f32x4;
typedef __attribute__((ext_vector_type(4))) unsigned short us4;

__device__ __forceinline__ float bfu2f(unsigned short u) {
  union { unsigned int i; float f; } c; c.i = ((unsigned int)u) << 16; return c.f;
}
__device__ __forceinline__ unsigned short f2bfu(float f) {
  union { float f; unsigned int i; } c; c.f = f;
  return (unsigned short)((c.i + 0x7FFFu + ((c.i >> 16) & 1u)) >> 16);
}
__device__ __forceinline__ void async16(void* lds, const void* g) {
  __builtin_amdgcn_global_load_lds(
      (const __attribute__((address_space(1))) unsigned int*)g,
      (__attribute__((address_space(3))) unsigned int*)lds, 16, 0, 0);
}

// ---------------- cast fp32 -> bf16 for x and Wv in one dispatch ----------------
__global__ void cast_xw_kernel(const float* __restrict__ x, const float* __restrict__ Wv,
                               unsigned short* __restrict__ xb,
                               unsigned short* __restrict__ Wvb, int x4) {
  int i = blockIdx.x * blockDim.x + threadIdx.x;
  const float* in; unsigned short* out; int j;
  if (i < x4) { in = x; out = xb; j = i; }
  else { in = Wv; out = Wvb; j = i - x4; }
  f32x4 v = ((const f32x4*)in)[j];
  us4 o;
  o[0] = f2bfu(v[0]); o[1] = f2bfu(v[1]); o[2] = f2bfu(v[2]); o[3] = f2bfu(v[3]);
  ((us4*)out)[j] = o;
}

// ---------------- transpose-cast: out[i,h] = bf16(in[h,i]) for Wq, Wk ----------------
__global__ void castT_kernel(const float* __restrict__ Wq, const float* __restrict__ Wk,
                             unsigned short* __restrict__ WqT,
                             unsigned short* __restrict__ WkT) {
  const float* in = (blockIdx.z == 0) ? Wq : Wk;
  unsigned short* out = (blockIdx.z == 0) ? WqT : WkT;
  __shared__ float t[64][65];
  const int h0 = blockIdx.x * 64, i0 = blockIdx.y * 64;
  const int tid = threadIdx.x;
  const int sub = tid >> 4, c4 = tid & 15;
#pragma unroll
  for (int p = 0; p < 4; ++p) {
    const int row = p * 16 + sub;
    f32x4 v = *(const f32x4*)(in + (size_t)(h0 + row) * DIM + i0 + c4 * 4);
    t[row][c4 * 4 + 0] = v[0]; t[row][c4 * 4 + 1] = v[1];
    t[row][c4 * 4 + 2] = v[2]; t[row][c4 * 4 + 3] = v[3];
  }
  __syncthreads();
#pragma unroll
  for (int p = 0; p < 4; ++p) {
    const int orow = p * 16 + sub;
    us4 o;
    o[0] = f2bfu(t[c4 * 4 + 0][orow]);
    o[1] = f2bfu(t[c4 * 4 + 1][orow]);
    o[2] = f2bfu(t[c4 * 4 + 2][orow]);
    o[3] = f2bfu(t[c4 * 4 + 3][orow]);
    *(us4*)(out + (size_t)(i0 + orow) * DIM + h0 + c4 * 4) = o;
  }
}

// ---------------- t1 = WqT·bk, t2 = WkT·bq (row-dots) ----------------
__global__ void t12_kernel(const unsigned short* __restrict__ WqT,
                           const unsigned short* __restrict__ WkT,
                           const float* __restrict__ bq, const float* __restrict__ bk,
                           float* __restrict__ t1, float* __restrict__ t2) {
  const int y = blockIdx.y;
  const unsigned short* Wt = y ? WkT : WqT;
  const float* vec = y ? bq : bk;
  float* tout = y ? t2 : t1;
  const int wave = threadIdx.x >> 6, lane = threadIdx.x & 63;
  const int i = blockIdx.x * 4 + wave;
  const us4* wr = (const us4*)(Wt + (size_t)i * DIM);
  float s = 0.f;
#pragma unroll
  for (int t = 0; t < 4; ++t) {
    us4 w4 = wr[lane + 64 * t];
    f32x4 b4 = *(const f32x4*)(vec + (lane + 64 * t) * 4);
    s += bfu2f(w4[0]) * b4[0] + bfu2f(w4[1]) * b4[1] +
         bfu2f(w4[2]) * b4[2] + bfu2f(w4[3]) * b4[3];
  }
#pragma unroll
  for (int o = 32; o; o >>= 1) s += __shfl_down(s, o);
  if (lane == 0) tout[i] = s;
}

// ---------------- a[bn]=scale*(x_row·t1 + bq·bk); c[bn]=scale*(x_row·t2) ----------------
__global__ void ac_kernel(const unsigned short* __restrict__ xb,
                          const float* __restrict__ t1, const float* __restrict__ t2,
                          const float* __restrict__ bq, const float* __restrict__ bk,
                          float* __restrict__ a, float* __restrict__ c) {
  const float scale = 0.03125f;
  const int tid = threadIdx.x;
  const int wave = tid >> 6, lane = tid & 63;
  float dp = 0.f;
  for (int i = tid; i < DIM; i += 256) dp += bq[i] * bk[i];
#pragma unroll
  for (int o = 32; o; o >>= 1) dp += __shfl_down(dp, o);
  __shared__ float dred[4];
  if ((tid & 63) == 0) dred[tid >> 6] = dp;
  __syncthreads();
  const float d = dred[0] + dred[1] + dred[2] + dred[3];
  float t1r[16], t2r[16];
#pragma unroll
  for (int t = 0; t < 4; ++t) {
    f32x4 v1 = *(const f32x4*)(t1 + (lane + 64 * t) * 4);
    f32x4 v2 = *(const f32x4*)(t2 + (lane + 64 * t) * 4);
#pragma unroll
    for (int j = 0; j < 4; ++j) { t1r[t * 4 + j] = v1[j]; t2r[t * 4 + j] = v2[j]; }
  }
  for (int rr = 0; rr < 16; ++rr) {
    const int row = blockIdx.x * 64 + wave * 16 + rr;
    const us4* xr = (const us4*)(xb + (size_t)row * DIM);
    float sa = 0.f, sc = 0.f;
#pragma unroll
    for (int t = 0; t < 4; ++t) {
      us4 v = xr[lane + 64 * t];
#pragma unroll
      for (int j = 0; j < 4; ++j) {
        const float f = bfu2f(v[j]);
        sa += f * t1r[t * 4 + j];
        sc += f * t2r[t * 4 + j];
      }
    }
#pragma unroll
    for (int o = 32; o; o >>= 1) { sa += __shfl_down(sa, o); sc += __shfl_down(sc, o); }
    if (lane == 0) {
      a[row] = scale * (sa + d);
      c[row] = scale * sc;
    }
  }
}

// ---------------- path-pool weights w[b,j]; zero-inits denom (+zbias via block 0) ----------------
__global__ void pathw_kernel(const int* __restrict__ pos, float* __restrict__ w,
                             float* __restrict__ denom, float* __restrict__ zbias) {
  const int b = blockIdx.x;
  __shared__ int ps[SEQ];
  __shared__ int mcnt;
  const int tid = threadIdx.x;
  if (tid == 0) mcnt = 0;
  __syncthreads();
  if (b == 0)
    for (int i = tid; i < DIM; i += 256) zbias[i] = 0.f;
  for (int i = tid; i < SEQ; i += 256) {
    ps[i] = pos[b * SEQ + i];
    denom[b * SEQ + i] = 0.f;
  }
  __syncthreads();
  int c = 0;
  for (int i = tid; i < SEQ; i += 256) c += ps[i];
  for (int o = 32; o; o >>= 1) c += __shfl_down(c, o);
  if ((tid & 63) == 0) atomicAdd(&mcnt, c);
  __syncthreads();
  const float invM = 1.0f / (float)mcnt;
  for (int j = tid; j < SEQ; j += 256) {
    float a = 0.f;
#pragma unroll
    for (int di = -1; di <= 1; ++di) {
      int i = j + di;
      if (i < 0 || i >= SEQ) continue;
      if (!ps[i]) continue;
      int s, e;
      if (i < 2) { s = 0; e = (i == 0) ? 2 : 3; }
      else { s = (ps[i - 2] == 1) ? i : (i - 1); e = i + 2; if (e > SEQ) e = SEQ; }
      if (s <= j && j < e) a += 1.0f / (float)(e - s);
    }
    w[b * SEQ + j] = a * invM;
  }
}

// ---------------- bf16 NT GEMM: C = bf16((A @ W^T + bias)*alpha) ----------------
// 2-phase double-buffered K-loop: prefetch tile k+1 while computing tile k;
// single __syncthreads per iter (its vmcnt drain covers loads issued one
// compute-phase earlier). f32 LDS-restage epilogue overlays buffer 0.
__global__ void proj_gemm(const unsigned short* __restrict__ A,
                          const unsigned short* __restrict__ W,
                          const float* __restrict__ bias, float alpha,
                          unsigned short* __restrict__ C, int M, int N, int K)
{
  __shared__ __align__(16) char smem[32768];   // 2 x (As 8K + Bs 8K); Sl overlays
  float* Sl = (float*)smem;                    // 32*132*4 = 16896
  const int tid = threadIdx.x;
  const int wave = tid >> 6, lane = tid & 63;
  const int lr = lane & 15, lg = lane >> 4;
  const int wr = wave >> 1, wc = wave & 1;
  const int flat = blockIdx.x + gridDim.x * blockIdx.y;
  const int q8 = (gridDim.x * gridDim.y) >> 3;
  const int t = (flat & 7) * q8 + (flat >> 3);
  const int m0 = (t / gridDim.y) * 128;
  const int n0 = (t % gridDim.y) * 128;
  const int off0 = tid * 16, off1 = 4096 + tid * 16;
  const int r0 = off0 >> 6, ke0 = (off0 >> 1) & 31;
  const int r1 = off1 >> 6, ke1 = (off1 >> 1) & 31;
  f32x4 acc[4][4] = {};

  auto stage = [&](char* base, int kk) {
    async16(base + off0, A + (size_t)(m0 + r0) * K + kk + ke0);
    async16(base + off1, A + (size_t)(m0 + r1) * K + kk + ke1);
    async16(base + 8192 + off0, W + (size_t)(n0 + r0) * K + kk + ke0);
    async16(base + 8192 + off1, W + (size_t)(n0 + r1) * K + kk + ke1);
  };
  auto compute = [&](const char* base) {
    bf16x8 af[4], bfv[4];
#pragma unroll
    for (int i = 0; i < 4; ++i) {
      af[i]  = *(const bf16x8*)(base + ((wr * 64 + i * 16 + lr) << 6) + (lg << 4));
      bfv[i] = *(const bf16x8*)(base + 8192 + ((wc * 64 + i * 16 + lr) << 6) + (lg << 4));
    }
#pragma unroll
    for (int i = 0; i < 4; ++i)
#pragma unroll
      for (int j = 0; j < 4; ++j)
        acc[i][j] = __builtin_amdgcn_mfma_f32_16x16x32_bf16(af[i], bfv[j], acc[i][j], 0, 0, 0);
  };

  const int nt = K >> 5;
  stage(smem, 0);
  __syncthreads();
  int cur = 0;
  for (int k = 0; k < nt - 1; ++k) {
    stage(smem + ((cur ^ 1) << 14), (k + 1) << 5);   // prefetch next tile
    compute(smem + (cur << 14));                     // compute current
    __syncthreads();                                 // drain prefetch + sync
    cur ^= 1;
  }
  compute(smem + (cur << 14));
#pragma unroll
  for (int p = 0; p < 4; ++p) {
    __syncthreads();
    if (wr == (p >> 1)) {
      const int ibase = (p & 1) * 2;
#pragma unroll
      for (int ii = 0; ii < 2; ++ii) {
        const int i = ibase + ii;
#pragma unroll
        for (int j = 0; j < 4; ++j)
#pragma unroll
          for (int r = 0; r < 4; ++r)
            Sl[(ii * 16 + lg * 4 + r) * 132 + wc * 64 + j * 16 + lr] = acc[i][j][r];
      }
    }
    __syncthreads();
#pragma unroll
    for (int it = 0; it < 4; ++it) {
      const int v = tid + it * 256;
      const int lrow = v >> 5, c4 = v & 31;
      const int grow = m0 + p * 32 + lrow;
      const int col = n0 + c4 * 4;
      const f32x4 s4 = *(const f32x4*)(&Sl[lrow * 132 + c4 * 4]);
      const f32x4 b4 = *(const f32x4*)(bias + col);
      us4 o;
      o[0] = f2bfu((s4[0] + b4[0]) * alpha);
      o[1] = f2bfu((s4[1] + b4[1]) * alpha);
      o[2] = f2bfu((s4[2] + b4[2]) * alpha);
      o[3] = f2bfu((s4[3] + b4[3]) * alpha);
      *(us4*)(C + (size_t)grow * N + col) = o;
    }
  }
}

// ---------------- per-batch E = exp(z@x^T + a_n + c_m + atom + var), fused rowsum ----
// 2-phase double-buffered K-loop + single bf16 full-tile restage + MLP-batched
// epilogue. XCD swizzle: XCD j owns batches {2j,2j+1}.
__global__ void qk_exp_kernel(const unsigned short* __restrict__ z,
                              const unsigned short* __restrict__ xb,
                              const float* __restrict__ ag,
                              const float* __restrict__ vg,
                              const float* __restrict__ av,
                              const float* __restrict__ cv,
                              unsigned short* __restrict__ E,
                              float* __restrict__ denom)
{
  __shared__ __align__(16) char smem[33792];  // max(2x16K dbuf, Slb=128*132*2)
  unsigned short* Slb = (unsigned short*)smem;
  const int flat = blockIdx.x + 8 * blockIdx.y + 64 * blockIdx.z;
  const int t = (flat & 7) * 128 + (flat >> 3);
  const int b = t >> 6;
  const int m0 = (t & 7) * 128;
  const int n0 = ((t >> 3) & 7) * 128;
  const unsigned short* Aq = z + ((size_t)b << 20);
  const unsigned short* Bk = xb + ((size_t)b << 20);
  const int tid = threadIdx.x;
  const int wave = tid >> 6, lane = tid & 63;
  const int lr = lane & 15, lg = lane >> 4;
  const int wr = wave >> 1, wc = wave & 1;
  const int off0 = tid * 16, off1 = 4096 + tid * 16;
  const int r0 = off0 >> 6, ke0 = (off0 >> 1) & 31;
  const int r1 = off1 >> 6, ke1 = (off1 >> 1) & 31;
  f32x4 acc[4][4] = {};

  auto stage = [&](char* base, int kk) {
    async16(base + off0, Aq + (size_t)(m0 + r0) * DIM + kk + ke0);
    async16(base + off1, Aq + (size_t)(m0 + r1) * DIM + kk + ke1);
    async16(base + 8192 + off0, Bk + (size_t)(n0 + r0) * DIM + kk + ke0);
    async16(base + 8192 + off1, Bk + (size_t)(n0 + r1) * DIM + kk + ke1);
  };
  auto compute = [&](const char* base) {
    bf16x8 af[4], bfv[4];
#pragma unroll
    for (int i = 0; i < 4; ++i) {
      af[i]  = *(const bf16x8*)(base + ((wr * 64 + i * 16 + lr) << 6) + (lg << 4));
      bfv[i] = *(const bf16x8*)(base + 8192 + ((wc * 64 + i * 16 + lr) << 6) + (lg << 4));
    }
#pragma unroll
    for (int i = 0; i < 4; ++i)
#pragma unroll
      for (int j = 0; j < 4; ++j)
        acc[i][j] = __builtin_amdgcn_mfma_f32_16x16x32_bf16(af[i], bfv[j], acc[i][j], 0, 0, 0);
  };

  stage(smem, 0);
  __syncthreads();
  int cur = 0;
  for (int k = 0; k < 31; ++k) {
    stage(smem + ((cur ^ 1) << 14), (k + 1) << 5);
    compute(smem + (cur << 14));
    __syncthreads();
    cur ^= 1;
  }
  compute(smem + (cur << 14));
  __syncthreads();          // all MFMA/ds_reads done before Slb overlay
  // ---- single full-tile restage as bf16 ----
#pragma unroll
  for (int i = 0; i < 4; ++i)
#pragma unroll
    for (int j = 0; j < 4; ++j)
#pragma unroll
      for (int r = 0; r < 4; ++r)
        Slb[(wr * 64 + i * 16 + lg * 4 + r) * 132 + wc * 64 + j * 16 + lr] =
            f2bfu(acc[i][j][r]);
  __syncthreads();
  const float* agb = ag + ((size_t)b << 20);
  const float* vgb = vg + ((size_t)b << 20);
  unsigned short* Eb = E + ((size_t)b << 20);
  float* dnb = denom + b * SEQ;
  const float* avb = av + b * SEQ;
  const float* cvb = cv + b * SEQ;
  // ---- epilogue: 16 chunks, batches of 4, loads issued up-front ----
#pragma unroll
  for (int bt = 0; bt < 4; ++bt) {
    f32x4 a4[4], g4[4];
    int lrow[4];
    size_t basev[4];
#pragma unroll
    for (int q = 0; q < 4; ++q) {
      const int v = tid + (bt * 4 + q) * 256;     // 0..4095 = 128 rows x 32 col-quads
      lrow[q] = v >> 5;
      const int c4 = v & 31;
      basev[q] = (size_t)(m0 + lrow[q]) * SEQ + n0 + c4 * 4;
      a4[q] = *(const f32x4*)(agb + basev[q]);
      g4[q] = *(const f32x4*)(vgb + basev[q]);
    }
#pragma unroll
    for (int q = 0; q < 4; ++q) {
      const int v = tid + (bt * 4 + q) * 256;
      const int c4 = v & 31;
      const f32x4 c4v = *(const f32x4*)(cvb + n0 + c4 * 4);
      const float arow = avb[m0 + lrow[q]];
      const us4 sv = *(const us4*)(&Slb[lrow[q] * 132 + c4 * 4]);
      const float e0 = __expf(bfu2f(sv[0]) + a4[q][0] + g4[q][0] + arow + c4v[0]);
      const float e1 = __expf(bfu2f(sv[1]) + a4[q][1] + g4[q][1] + arow + c4v[1]);
      const float e2 = __expf(bfu2f(sv[2]) + a4[q][2] + g4[q][2] + arow + c4v[2]);
      const float e3 = __expf(bfu2f(sv[3]) + a4[q][3] + g4[q][3] + arow + c4v[3]);
      us4 o;
      o[0] = f2bfu(e0); o[1] = f2bfu(e1); o[2] = f2bfu(e2); o[3] = f2bfu(e3);
      *(us4*)(Eb + basev[q]) = o;
      float rs = e0 + e1 + e2 + e3;
#pragma unroll
      for (int o2 = 16; o2; o2 >>= 1) rs += __shfl_down(rs, o2, 32);
      if ((tid & 31) == 0) atomicAdd(&dnb[m0 + lrow[q]], rs);
    }
  }
}

// ---------------- weighted column partial: part[b][nc][m] = sum_{n in chunk} c_n*Mt[b,n,m]
__global__ void wcol_kernel(const unsigned short* __restrict__ Mt,
                            const float* __restrict__ wv,
                            const float* __restrict__ dv,
                            float* __restrict__ part) {
  const int nc = blockIdx.x;           // 16 chunks of 64 n
  const int b = blockIdx.y;
  const int tid = threadIdx.x;
  __shared__ float c[64];
  if (tid < 64) {
    const int n = nc * 64 + tid;
    float cvw = wv[b * SEQ + n];
    if (dv) cvw /= dv[b * SEQ + n];
    c[tid] = cvw;
  }
  __syncthreads();
  const unsigned short* p = Mt + ((size_t)b << 20) + ((size_t)(nc * 64) << 10) + tid * 4;
  f32x4 acc = {0.f, 0.f, 0.f, 0.f};
#pragma unroll 8
  for (int n = 0; n < 64; ++n) {
    const us4 v = *(const us4*)(p + ((size_t)n << 10));
    const float cn = c[n];
    acc[0] += cn * bfu2f(v[0]); acc[1] += cn * bfu2f(v[1]);
    acc[2] += cn * bfu2f(v[2]); acc[3] += cn * bfu2f(v[3]);
  }
  *(f32x4*)(part + (size_t)((b * 16 + nc) << 10) + tid * 4) = acc;
}

// ---------------- reduce part -> vec[b][m]; optionally also su[b] ----------------
__global__ void wred_kernel(const float* __restrict__ part, float* __restrict__ vec,
                            float* __restrict__ su) {
  const int b = blockIdx.x;
  const int tid = threadIdx.x;
  f32x4 s = {0.f, 0.f, 0.f, 0.f};
#pragma unroll
  for (int nc = 0; nc < 16; ++nc) {
    const f32x4 v = *(const f32x4*)(part + (size_t)((b * 16 + nc) << 10) + tid * 4);
    s[0] += v[0]; s[1] += v[1]; s[2] += v[2]; s[3] += v[3];
  }
  *(f32x4*)(vec + b * SEQ + tid * 4) = s;
  if (su) {
    float ts = s[0] + s[1] + s[2] + s[3];
#pragma unroll
    for (int o = 32; o; o >>= 1) ts += __shfl_down(ts, o);
    __shared__ float red[4];
    if ((tid & 63) == 0) red[tid >> 6] = ts;
    __syncthreads();
    if (tid == 0) su[b] = red[0] + red[1] + red[2] + red[3];
  }
}

// ---------------- item[b,h] = sum_d y[b,d]*Wv[h,d] + su[b]*bv[h] ----------------
__global__ void item_kernel(const float* __restrict__ y, const float* __restrict__ su,
                            const unsigned short* __restrict__ Wvb,
                            const float* __restrict__ bv, float* __restrict__ item) {
  const int b = blockIdx.x;
  const int hblk = blockIdx.y;
  __shared__ float ys[DIM];
  const int tid = threadIdx.x;
  for (int i = tid; i < DIM; i += 256) ys[i] = y[b * DIM + i];
  __syncthreads();
  const float sub = su[b];
  const int wave = tid >> 6, lane = tid & 63;
  const int h = hblk * 4 + wave;
  const us4* wrow = (const us4*)(Wvb + (size_t)h * DIM);
  float acc = 0.f;
#pragma unroll
  for (int t = 0; t < 4; ++t) {
    us4 v = wrow[t * 64 + lane];
    const int d0 = (t * 64 + lane) * 4;
    acc += ys[d0] * bfu2f(v[0]) + ys[d0 + 1] * bfu2f(v[1]) +
           ys[d0 + 2] * bfu2f(v[2]) + ys[d0 + 3] * bfu2f(v[3]);
  }
  for (int o = 32; o; o >>= 1) acc += __shfl_down(acc, o);
  if (lane == 0) item[b * DIM + h] = acc + sub * bv[h];
}

// ---------------- broadcast item[b,:] over n ----------------
__global__ void bcast_kernel(const float* __restrict__ item, float* __restrict__ out) {
  const int b = blockIdx.y;
  const int n = blockIdx.x;
  const f32x4* src = (const f32x4*)(item + b * DIM);
  f32x4* dst = (f32x4*)(out + (((size_t)b * SEQ + n) << 10));
  dst[threadIdx.x] = src[threadIdx.x];
}

extern "C" void kernel_launch(void* const* d_in, const int* in_sizes, int n_in,
                              void* d_out, int out_size, void* d_ws, size_t ws_size,
                              hipStream_t stream) {
  const float* x    = (const float*)d_in[0];
  const float* ag   = (const float*)d_in[1];
  const float* vgr  = (const float*)d_in[2];
  const float* Wq   = (const float*)d_in[3];
  const float* bq   = (const float*)d_in[4];
  const float* Wk   = (const float*)d_in[5];
  const float* bk   = (const float*)d_in[6];
  const float* Wv   = (const float*)d_in[7];
  const float* bv   = (const float*)d_in[8];
  const int*   pos  = (const int*)d_in[9];
  float* out = (float*)d_out;

  char* ws = (char*)d_ws;
  size_t off = 0;
  auto alloc = [&](size_t bytes) { void* p = ws + off; off += (bytes + 255) & ~(size_t)255; return p; };
  const size_t BNH = (size_t)BATCH * SEQ * DIM;
  unsigned short* xb   = (unsigned short*)alloc(BNH * 2);
  unsigned short* zb   = (unsigned short*)alloc(BNH * 2);
  unsigned short* E    = (unsigned short*)alloc(BNH * 2);
  unsigned short* WqT  = (unsigned short*)alloc((size_t)DIM * DIM * 2);
  unsigned short* WkT  = (unsigned short*)alloc((size_t)DIM * DIM * 2);
  unsigned short* Wvb  = (unsigned short*)alloc((size_t)DIM * DIM * 2);
  unsigned short* Hb   = (unsigned short*)alloc((size_t)DIM * DIM * 2);
  float* w     = (float*)alloc((size_t)BATCH * SEQ * 4);
  float* denom = (float*)alloc((size_t)BATCH * SEQ * 4);
  float* u     = (float*)alloc((size_t)BATCH * SEQ * 4);
  float* av    = (float*)alloc((size_t)BATCH * SEQ * 4);
  float* cvv   = (float*)alloc((size_t)BATCH * SEQ * 4);
  float* t1    = (float*)alloc((size_t)DIM * 4);
  float* t2    = (float*)alloc((size_t)DIM * 4);
  float* zbias = (float*)alloc((size_t)DIM * 4);
  float* y     = (float*)alloc((size_t)BATCH * DIM * 4);
  float* su    = (float*)alloc((size_t)BATCH * 4);
  float* item  = (float*)alloc((size_t)BATCH * DIM * 4);
  float* part  = (float*)alloc((size_t)BATCH * 16 * SEQ * 4);

  const float scale = 0.03125f;  // 1024^-0.5
  const int x4 = (int)(BNH / 4);

  // casts: x+Wv (one dispatch), Wq/Wk transposed
  cast_xw_kernel<<<(x4 + DIM * DIM / 4) / 256, 256, 0, stream>>>(x, Wv, xb, Wvb, x4);
  castT_kernel<<<dim3(16, 16, 2), 256, 0, stream>>>(Wq, Wk, WqT, WkT);

  // path-pool weights (+ denom/zbias zero-init)
  pathw_kernel<<<BATCH, 256, 0, stream>>>(pos, w, denom, zbias);

  // bias-fold vectors
  t12_kernel<<<dim3(256, 2), 256, 0, stream>>>(WqT, WkT, bq, bk, t1, t2);
  ac_kernel<<<256, 256, 0, stream>>>(xb, t1, t2, bq, bk, av, cvv);

  // H = scale * (Wk^T Wq)
  proj_gemm<<<dim3(8, 8), 256, 0, stream>>>(WkT, WqT, zbias, scale, Hb, DIM, DIM, DIM);

  // z = x @ H^T
  proj_gemm<<<dim3(128, 8), 256, 0, stream>>>(xb, Hb, zbias, 1.0f, zb,
                                              BATCH * SEQ, DIM, DIM);

  // E = exp(z x^T + a + c + graphs), denom += rowsums
  qk_exp_kernel<<<dim3(8, 8, BATCH), 256, 0, stream>>>(zb, xb, ag, vgr, av, cvv, E, denom);

  // u[b,m] = sum_n (w/denom)[b,n] * E[b,n,m]; su[b] = sum_m u
  wcol_kernel<<<dim3(16, BATCH), 256, 0, stream>>>(E, w, denom, part);
  wred_kernel<<<BATCH, 256, 0, stream>>>(part, u, su);

  // y[b,d] = sum_m u[b,m] * x[b,m,d]
  wcol_kernel<<<dim3(16, BATCH), 256, 0, stream>>>(xb, u, nullptr, part);
  wred_kernel<<<BATCH, 256, 0, stream>>>(part, y, nullptr);

  // item[b,h] = y@Wv^T + su*bv
  item_kernel<<<dim3(BATCH, 256), 256, 0, stream>>>(y, su, Wvb, bv, item);

  // broadcast to [B,N,H]
  bcast_kernel<<<dim3(SEQ, BATCH), 256, 0, stream>>>(item, out);
}